// Round 6
// baseline (395.213 us; speedup 1.0000x reference)
//
#include <hip/hip_runtime.h>

// N=50000, D=128 (both layers), K=256, EH=500000, ES=250000.
#define D_FEAT 128
#define K_DIM  256
#define EPB 4096
#define PADL 136   // LDS leading dim (ushorts) for the 32x128 epilogue tile; 272B row, 16B-aligned

// ---- fragment-major layouts (eliminates 64-line address divergence in GEMMs) ----
// Wb (layer L, NT tiles): slot ((k0*NT + T)*64 + lane) * 8 shorts
//   = W[T*16 + (lane&15)][k0*32 + (lane>>4)*8 .. +8]
// z  (A operand):        slot ((G*8 + k0)*64 + lane) * 8 shorts,  G = row group of 16
//   = z_row[G*16 + (lane&15)][k0*32 + (lane>>4)*8 .. +8]

typedef __attribute__((ext_vector_type(8))) short bf16x8;
typedef __attribute__((ext_vector_type(4))) float f32x4;
typedef __attribute__((ext_vector_type(2))) float f32x2;

__device__ __forceinline__ unsigned short f2b(float f) {
    union { float f; unsigned u; } cv; cv.f = f;
    return (unsigned short)((cv.u + 0x7fffu + ((cv.u >> 16) & 1u)) >> 16);
}

__device__ __forceinline__ unsigned pack2(float lo, float hi) {
    return (unsigned)f2b(lo) | ((unsigned)f2b(hi) << 16);
}

__device__ __forceinline__ uint4 pack8(float4 a, float4 b) {
    return make_uint4(pack2(a.x, a.y), pack2(a.z, a.w), pack2(b.x, b.y), pack2(b.z, b.w));
}

// unpack one u32 (2 bf16) into a packed float2 -> enables v_pk_add_f32 accumulation
__device__ __forceinline__ f32x2 up2(unsigned u) {
    union { unsigned u; float f; } lo, hi;
    lo.u = u << 16; hi.u = u & 0xffff0000u;
    f32x2 r; r.x = lo.f; r.y = hi.f; return r;
}

__device__ __forceinline__ void addu4p(f32x2* a, uint4 v) {
    a[0] += up2(v.x); a[1] += up2(v.y); a[2] += up2(v.z); a[3] += up2(v.w);
}

__device__ __forceinline__ float blo(unsigned u) { union { unsigned u; float f; } c; c.u = u << 16; return c.f; }
__device__ __forceinline__ float bhi(unsigned u) { union { unsigned u; float f; } c; c.u = u & 0xffff0000u; return c.f; }

// edge-array offset within the concatenated [H0|S0|H1|S1] space
__device__ __forceinline__ long yoff(int y, int EH, int ES) {
    return (long)((y + 1) >> 1) * EH + (long)(y >> 1) * ES;
}

// ---------------- fused head: prep_static + conv_weights + node-level histogram ----------------
// blocks [0, prepb)            : bf16 prep (streaming, BW-bound)
// blocks [prepb, prepb+16)     : weight conversion to fragment-major
// blocks [prepb+16, +4*binb)   : per-node edge histogram via global atomics (latency-bound)
// Independent work fused into one dispatch: streaming overlaps the atomic stream.
__global__ __launch_bounds__(256)
void head(const float4* __restrict__ x, const float4* __restrict__ hbar0,
          const float4* __restrict__ hbar1,
          uint4* __restrict__ hb0, uint4* __restrict__ db0,
          uint4* __restrict__ hb1, uint4* __restrict__ z, int n16,
          const float* __restrict__ W0, unsigned short* __restrict__ WbF0,
          const float* __restrict__ W1, unsigned short* __restrict__ WbF1,
          const int* __restrict__ hd0, const int* __restrict__ sd0,
          const int* __restrict__ hd1, const int* __restrict__ sd1,
          int EH, int ES, int* __restrict__ cnt, int n, int prepb, int binb) {
    int bid = blockIdx.x;
    int t = threadIdx.x;
    if (bid < prepb) {
        int i = bid * 256 + t;
        if (i >= n16) return;
        float4 xa = x[i * 2],     xb = x[i * 2 + 1];
        float4 ba = hbar0[i * 2], bb = hbar0[i * 2 + 1];
        float4 ca = hbar1[i * 2], cb = hbar1[i * 2 + 1];
        hb0[i] = pack8(ba, bb);
        db0[i] = pack8(make_float4(xa.x - ba.x, xa.y - ba.y, xa.z - ba.z, xa.w - ba.w),
                       make_float4(xb.x - bb.x, xb.y - bb.y, xb.z - bb.z, xb.w - bb.w));
        hb1[i] = pack8(ca, cb);
        int g = i >> 4, seg = i & 15;
        int G = g >> 4, r = g & 15, k0 = seg >> 2, kq = seg & 3;
        z[((size_t)G * 8 + k0) * 64 + kq * 16 + r] = pack8(xa, xb);   // fragment-major
    } else if (bid < prepb + 16) {
        int i = (bid - prepb) * 256 + t;
        if (i < 4096) {
            int k0 = i >> 9, T = (i >> 6) & 7, lane = i & 63;
            int col = T * 16 + (lane & 15);
            int kb = k0 * 32 + (lane >> 4) * 8;
            const float* src = W0 + (size_t)col * 256 + kb;
            unsigned short* dst = WbF0 + (size_t)i * 8;
            #pragma unroll
            for (int e = 0; e < 8; ++e) dst[e] = f2b(src[e]);
        }
        if (i < 1536) {
            int k0 = i / 192, rem = i % 192;
            int T = rem >> 6, lane = rem & 63;
            int col = T * 16 + (lane & 15);
            int kb = k0 * 32 + (lane >> 4) * 8;
            unsigned short* dst = WbF1 + (size_t)i * 8;
            #pragma unroll
            for (int e = 0; e < 8; ++e)
                dst[e] = (col < 47) ? f2b(W1[(size_t)col * 256 + kb + e]) : (unsigned short)0;
        }
    } else {
        int r = bid - prepb - 16;
        int y = r / binb, c = r % binb;
        const int* d = (y == 0) ? hd0 : (y == 1) ? sd0 : (y == 2) ? hd1 : sd1;
        int E = (y & 1) ? ES : EH;
        int* cn = cnt + (size_t)y * n;
        int i0 = c * EPB;
        #pragma unroll
        for (int j = 0; j < 16; ++j) {
            int i = i0 + j * 256 + t;
            if (i < E) atomicAdd(&cn[d[i]], 1);
        }
    }
}

// ---------------- per-bucket (256-node) exclusive scan of node counts ----------------
__global__ __launch_bounds__(256)
void scanN(const int* __restrict__ cnt, int* __restrict__ rpAll,
           int* __restrict__ bucketSum, int n, int nb2) {
    int y = blockIdx.y, b = blockIdx.x, t = threadIdx.x;
    int node = b * 256 + t;
    __shared__ int sh[256];
    int c = (node < n) ? cnt[(size_t)y * n + node] : 0;
    sh[t] = c;
    __syncthreads();
    for (int o = 1; o < 256; o <<= 1) {
        int v = (t >= o) ? sh[t - o] : 0;
        __syncthreads();
        sh[t] += v;
        __syncthreads();
    }
    if (node < n) rpAll[(size_t)y * (n + 1) + node] = sh[t] - c;  // bucket-local exclusive
    if (t == 255) bucketSum[y * nb2 + b] = sh[255];
}

// ---------------- scan of bucket sums (one block per etype) ----------------
__global__ __launch_bounds__(256)
void scanB(const int* __restrict__ bucketSum, int* __restrict__ rpBucket, int nb2) {
    int y = blockIdx.x, t = threadIdx.x;
    __shared__ int sh[256];
    int c = (t < nb2) ? bucketSum[y * nb2 + t] : 0;
    sh[t] = c;
    __syncthreads();
    for (int o = 1; o < 256; o <<= 1) {
        int v = (t >= o) ? sh[t - o] : 0;
        __syncthreads();
        sh[t] += v;
        __syncthreads();
    }
    if (t < nb2) rpBucket[y * (nb2 + 1) + t] = sh[t] - c;  // exclusive bucket base
}

// ---------------- add bucket base -> final rp; init scatter cursors ----------------
__global__ __launch_bounds__(256)
void baseFix(int* __restrict__ rpAll, int* __restrict__ cur,
             const int* __restrict__ rpBucket, int n, int nb2, int EH, int ES) {
    int y = blockIdx.y;
    int node = blockIdx.x * 256 + threadIdx.x;
    if (node < n) {
        int v = rpAll[(size_t)y * (n + 1) + node] + rpBucket[y * (nb2 + 1) + (node >> 8)];
        rpAll[(size_t)y * (n + 1) + node] = v;
        cur[(size_t)y * n + node] = v;
    }
    if (blockIdx.x == 0 && threadIdx.x == 0)
        rpAll[(size_t)y * (n + 1) + n] = (y & 1) ? ES : EH;
}

// ---------------- single-pass direct scatter (replaces binA + placeB) ----------------
__global__ __launch_bounds__(256)
void scatterE(const int* __restrict__ hs0, const int* __restrict__ hd0,
              const int* __restrict__ ss0, const int* __restrict__ sd0,
              const int* __restrict__ hs1, const int* __restrict__ hd1,
              const int* __restrict__ ss1, const int* __restrict__ sd1,
              int EH, int ES, int* __restrict__ cur, int* __restrict__ srcAll, int n) {
    int y = blockIdx.y;
    const int* src = (y == 0) ? hs0 : (y == 1) ? ss0 : (y == 2) ? hs1 : ss1;
    const int* dst = (y == 0) ? hd0 : (y == 1) ? sd0 : (y == 2) ? hd1 : sd1;
    int E = (y & 1) ? ES : EH;
    int* cn = cur + (size_t)y * n;
    int* sb = srcAll + yoff(y, EH, ES);
    int t = threadIdx.x;
    int i0 = blockIdx.x * EPB;
    #pragma unroll
    for (int j = 0; j < 16; ++j) {
        int i = i0 + j * 256 + t;
        if (i < E) {
            int slot = atomicAdd(&cn[dst[i]], 1);
            sb[slot] = src[i];
        }
    }
}

// ---------------- aggregation: one full wave per node ----------------
// 64 lanes = 4 edges (j = lane>>4) x 16 feature-segments (l = lane&15, 16B each).
// H and S edge streams interleaved in one pipeline; src indices prefetched one
// iteration ahead; packed f32x2 accumulation. (Proven 44 us / dispatch.)
__global__ __launch_bounds__(256)
void aggregate_z(const uint4* __restrict__ HB, const uint4* __restrict__ DB,
                 const int* __restrict__ rpH, const int* __restrict__ srcH,
                 const int* __restrict__ rpS, const int* __restrict__ srcS,
                 uint4* __restrict__ z, int n) {
    int g = blockIdx.x * 4 + (threadIdx.x >> 6);
    if (g >= n) return;
    int lane = threadIdx.x & 63;
    int j = lane >> 4, l = lane & 15;

    int hb_ = rpH[g], he = rpH[g + 1];
    int sb  = rpS[g], se = rpS[g + 1];
    int dH = he - hb_, dS = se - sb;
    int nIt = max((dH + 7) >> 3, (dS + 7) >> 3);

    f32x2 a[4] = {};
    f32x2 d[4] = {};

    int iH1 = hb_ + j, iH2 = hb_ + 4 + j;
    int iS1 = sb + j,  iS2 = sb + 4 + j;
    int sH1 = 0, sH2 = 0, sS1 = 0, sS2 = 0;
    if (iH1 < he) sH1 = srcH[iH1];
    if (iH2 < he) sH2 = srcH[iH2];
    if (iS1 < se) sS1 = srcS[iS1];
    if (iS2 < se) sS2 = srcS[iS2];

    for (int it = 0; it < nIt; ++it) {
        uint4 h1 = make_uint4(0, 0, 0, 0), h2 = make_uint4(0, 0, 0, 0);
        uint4 s1 = make_uint4(0, 0, 0, 0), s2 = make_uint4(0, 0, 0, 0);
        if (iH1 < he) h1 = HB[(size_t)sH1 * 16 + l];
        if (iH2 < he) h2 = HB[(size_t)sH2 * 16 + l];
        if (iS1 < se) s1 = DB[(size_t)sS1 * 16 + l];
        if (iS2 < se) s2 = DB[(size_t)sS2 * 16 + l];
        iH1 += 8; iH2 += 8; iS1 += 8; iS2 += 8;
        if (iH1 < he) sH1 = srcH[iH1];
        if (iH2 < he) sH2 = srcH[iH2];
        if (iS1 < se) sS1 = srcS[iS1];
        if (iS2 < se) sS2 = srcS[iS2];
        addu4p(a, h1); addu4p(a, h2);
        addu4p(d, s1); addu4p(d, s2);
    }

    float rH = 1.0f / fmaxf((float)dH, 1.0f);
    float rS = 1.0f / fmaxf((float)dS, 1.0f);
    float s[8];
    #pragma unroll
    for (int i = 0; i < 4; ++i) {
        float v0 = a[i].x * rH + d[i].x * rS;
        float v1 = a[i].y * rH + d[i].y * rS;
        v0 += __shfl_xor(v0, 16);
        v0 += __shfl_xor(v0, 32);
        v1 += __shfl_xor(v1, 16);
        v1 += __shfl_xor(v1, 32);
        s[2 * i] = v0;
        s[2 * i + 1] = v1;
    }
    if (j == 0) {
        // lane l holds k = 128 + l*8 .. +8  ->  fragment slot
        uint4 rv = make_uint4(pack2(s[0], s[1]), pack2(s[2], s[3]),
                              pack2(s[4], s[5]), pack2(s[6], s[7]));
        size_t slot = ((size_t)(g >> 4) * 8 + 4 + (l >> 2)) * 64 + (l & 3) * 16 + (g & 15);
        z[slot] = rv;
    }
}

// ---------------- MFMA GEMM layer 0: fused epilogue (LDS-transposed) ----------------
// Block: 256 thr = 4 waves; 32 rows/block. Wave (rt,ch): rows rt*16..+16, cols ch*64..+64.
// A and B read from fragment-major buffers: every load = contiguous 1KiB per wave.
__global__ __launch_bounds__(256, 2)
void gemm_mfma_l0(const unsigned short* __restrict__ Z, const unsigned short* __restrict__ Wb,
                  const float* __restrict__ bias, const float* __restrict__ hbar1,
                  unsigned short* __restrict__ db1, unsigned short* __restrict__ zl, int n) {
    __shared__ unsigned short hl[32 * PADL];
    int tid  = threadIdx.x;
    int wave = tid >> 6;
    int lane = tid & 63;
    int rt = wave >> 1;                 // row tile 0..1
    int ch = wave & 1;                  // col half 0..1
    int m0 = blockIdx.x * 32;
    int cl = lane & 15;
    int kq = lane >> 4;

    const short* Af = (const short*)Z;
    const short* Bf = (const short*)Wb;
    size_t G = (size_t)(m0 >> 4) + rt;

    // A row-slice: 8 coalesced fragment loads (32 VGPR, all in flight)
    bf16x8 aF[8];
    #pragma unroll
    for (int k0 = 0; k0 < 8; ++k0)
        aF[k0] = *(const bf16x8*)(Af + ((G * 8 + k0) * 64 + lane) * 8);

    f32x4 acc[4] = {};
    bf16x8 bF[2][4];
    #pragma unroll
    for (int t = 0; t < 4; ++t)
        bF[0][t] = *(const bf16x8*)(Bf + ((size_t)((0 * 8 + ch * 4 + t)) * 64 + lane) * 8);

    #pragma unroll
    for (int k0 = 0; k0 < 8; ++k0) {
        int cur = k0 & 1, nxt = cur ^ 1;
        if (k0 < 7) {
            #pragma unroll
            for (int t = 0; t < 4; ++t)
                bF[nxt][t] = *(const bf16x8*)(Bf + ((size_t)(((k0 + 1) * 8 + ch * 4 + t)) * 64 + lane) * 8);
        }
        #pragma unroll
        for (int t = 0; t < 4; ++t)
            acc[t] = __builtin_amdgcn_mfma_f32_16x16x32_bf16(aF[k0], bF[cur][t], acc[t], 0, 0, 0);
    }

    // stage h = relu(acc + bias) into LDS tile [32][PADL] (bf16)
    #pragma unroll
    for (int t = 0; t < 4; ++t) {
        int c = ch * 64 + t * 16 + cl;
        float bv = bias[c];
        #pragma unroll
        for (int r = 0; r < 4; ++r) {
            int row = rt * 16 + kq * 4 + r;
            hl[row * PADL + c] = f2b(fmaxf(acc[t][r] + bv, 0.0f));
        }
    }
    __syncthreads();

    // zl (layer-1 A operand) written FRAGMENT-MAJOR: 512 slots of 16B, coalesced.
    #pragma unroll
    for (int s = 0; s < 2; ++s) {
        int ls = tid + s * 256;
        int gi = ls >> 8, k0 = (ls >> 6) & 3, ln = ls & 63;
        int rl = gi * 16 + (ln & 15);
        int col = k0 * 32 + (ln >> 4) * 8;
        int m = m0 + rl;
        if (m < n) {
            uint4 v = *(const uint4*)(hl + rl * PADL + col);
            ((uint4*)zl)[((size_t)(m0 >> 4) + gi) * 8 * 64 + (size_t)k0 * 64 + ln] = v;
        }
    }

    // db1 = bf16(h - hbar1), row-major (gather target), coalesced
    int row  = tid >> 3;
    int col  = (tid & 7) * 16;
    int m    = m0 + row;
    if (m < n) {
        const uint4* hr = (const uint4*)(hl + row * PADL + col);
        uint4 v0 = hr[0];
        uint4 v1 = hr[1];
        const float4* hb = (const float4*)(hbar1 + (size_t)m * 128 + col);
        float4 h0 = hb[0], h1 = hb[1], h2 = hb[2], h3 = hb[3];
        uint4 d0, d1;
        d0.x = pack2(blo(v0.x) - h0.x, bhi(v0.x) - h0.y);
        d0.y = pack2(blo(v0.y) - h0.z, bhi(v0.y) - h0.w);
        d0.z = pack2(blo(v0.z) - h1.x, bhi(v0.z) - h1.y);
        d0.w = pack2(blo(v0.w) - h1.z, bhi(v0.w) - h1.w);
        d1.x = pack2(blo(v1.x) - h2.x, bhi(v1.x) - h2.y);
        d1.y = pack2(blo(v1.y) - h2.z, bhi(v1.y) - h2.w);
        d1.z = pack2(blo(v1.z) - h3.x, bhi(v1.z) - h3.y);
        d1.w = pack2(blo(v1.w) - h3.z, bhi(v1.w) - h3.w);
        uint4* dp = (uint4*)(db1 + (size_t)m * 128 + col);
        dp[0] = d0;
        dp[1] = d1;
    }
}

// ---------------- MFMA GEMM layer 1 -> f32 out ----------------
// 128-thread blocks (2 waves, 32 rows); fragment-major A and B.
template<int NT>
__global__ __launch_bounds__(128, 2)
void gemm_mfma(const unsigned short* __restrict__ Z, const unsigned short* __restrict__ Wb,
               const float* __restrict__ bias, float* __restrict__ out, int n, int COLS) {
    int wave = threadIdx.x >> 6;
    int lane = threadIdx.x & 63;
    int m0 = blockIdx.x * 32 + wave * 16;
    int cl = lane & 15;
    int kq = lane >> 4;

    const short* Af = (const short*)Z;
    const short* Bf = (const short*)Wb;
    size_t G = (size_t)(m0 >> 4);

    bf16x8 aF[8];
    #pragma unroll
    for (int k0 = 0; k0 < 8; ++k0)
        aF[k0] = *(const bf16x8*)(Af + ((G * 8 + k0) * 64 + lane) * 8);

    f32x4 acc[NT] = {};
    bf16x8 bF[2][NT];
    #pragma unroll
    for (int t = 0; t < NT; ++t)
        bF[0][t] = *(const bf16x8*)(Bf + ((size_t)(0 * NT + t) * 64 + lane) * 8);

    #pragma unroll
    for (int k0 = 0; k0 < 8; ++k0) {
        int cur = k0 & 1, nxt = cur ^ 1;
        if (k0 < 7) {
            #pragma unroll
            for (int t = 0; t < NT; ++t)
                bF[nxt][t] = *(const bf16x8*)(Bf + ((size_t)((k0 + 1) * NT + t) * 64 + lane) * 8);
        }
        #pragma unroll
        for (int t = 0; t < NT; ++t)
            acc[t] = __builtin_amdgcn_mfma_f32_16x16x32_bf16(aF[k0], bF[cur][t], acc[t], 0, 0, 0);
    }

    int rg = kq * 4;
    #pragma unroll
    for (int t = 0; t < NT; ++t) {
        int c = t * 16 + cl;
        if (c >= COLS) continue;
        float bv = bias[c];
        #pragma unroll
        for (int r = 0; r < 4; ++r) {
            int m = m0 + rg + r;
            if (m < n) out[(size_t)m * COLS + c] = fmaxf(acc[t][r] + bv, 0.f);
        }
    }
}

extern "C" void kernel_launch(void* const* d_in, const int* in_sizes, int n_in,
                              void* d_out, int out_size, void* d_ws, size_t ws_size,
                              hipStream_t stream) {
    const float* x     = (const float*)d_in[0];
    const float* hbar0 = (const float*)d_in[1];
    const float* hbar1 = (const float*)d_in[2];
    const float* W0    = (const float*)d_in[3];
    const float* b0    = (const float*)d_in[4];
    const float* W1    = (const float*)d_in[5];
    const float* b1    = (const float*)d_in[6];
    const int* hs0 = (const int*)d_in[7];
    const int* hd0 = (const int*)d_in[8];
    const int* ss0 = (const int*)d_in[9];
    const int* sd0 = (const int*)d_in[10];
    const int* hs1 = (const int*)d_in[11];
    const int* hd1 = (const int*)d_in[12];
    const int* ss1 = (const int*)d_in[13];
    const int* sd1 = (const int*)d_in[14];

    const int n   = in_sizes[0] / D_FEAT;   // 50000
    const int EH  = in_sizes[7];            // 500000
    const int ES  = in_sizes[9];            // 250000
    const int nb2 = (n + 255) / 256;        // 196 dst buckets per etype

    // ---- workspace layout ----
    int* cnt       = (int*)d_ws;                        // 4*n node counts
    int* cur       = cnt + 4 * (size_t)n;               // 4*n scatter cursors
    int* bucketSum = cur + 4 * (size_t)n;               // 4*nb2
    int* rpBucket  = bucketSum + 4 * nb2;               // 4*(nb2+1)
    int* rpAll     = rpBucket + 4 * (nb2 + 1);          // 4*(n+1)
    int* srcAll    = rpAll + 4 * (size_t)(n + 1);       // 2EH+2ES
    size_t int_words = 8 * (size_t)n + 4 * nb2 + 4 * (nb2 + 1) + 4 * (size_t)(n + 1)
                     + 2 * (size_t)EH + 2 * (size_t)ES;
    int_words = (int_words + 3) & ~(size_t)3;                          // 16 B align
    unsigned short* hb0 = (unsigned short*)((int*)d_ws + int_words);   // n*128 bf16
    unsigned short* db0 = hb0 + (size_t)n * D_FEAT;                    // n*128 bf16
    unsigned short* hb1 = db0 + (size_t)n * D_FEAT;                    // n*128 bf16
    unsigned short* db1 = hb1 + (size_t)n * D_FEAT;                    // n*128 bf16
    unsigned short* z   = db1 + (size_t)n * D_FEAT;                    // n*256 bf16 (+1 pad group)
    unsigned short* Wb0 = z + (size_t)n * K_DIM + 4096;                // 128*256 (pad: tail group reads)
    unsigned short* Wb1 = Wb0 + 128 * 256;                             // 64*256

    const int* rpH0 = rpAll;
    const int* rpS0 = rpAll + (size_t)(n + 1);
    const int* rpH1 = rpAll + 2 * (size_t)(n + 1);
    const int* rpS1 = rpAll + 3 * (size_t)(n + 1);
    int* srcH0 = srcAll;
    int* srcS0 = srcAll + (size_t)EH;
    int* srcH1 = srcAll + (size_t)EH + ES;
    int* srcS1 = srcAll + 2 * (size_t)EH + ES;

    dim3 blk(256);
    int binb  = (EH + EPB - 1) / EPB;       // 123
    int prepb = ((n * 16) + 255) / 256;     // 3125
    int aggb  = (n + 3) / 4;
    int gemmb0 = (n + 31) / 32;   // 32 rows per block (layer-0 GEMM)
    int gemmb1 = (n + 31) / 32;   // 32 rows per block (layer-1 GEMM, 128 thr)

    // ---- CSR build (single-pass scatter) + static prep ----
    hipMemsetAsync(cnt, 0, 4 * (size_t)n * sizeof(int), stream);
    head<<<prepb + 16 + 4 * binb, blk, 0, stream>>>(
        (const float4*)x, (const float4*)hbar0, (const float4*)hbar1,
        (uint4*)hb0, (uint4*)db0, (uint4*)hb1, (uint4*)z, n * 16,
        W0, Wb0, W1, Wb1, hd0, sd0, hd1, sd1, EH, ES, cnt, n, prepb, binb);
    scanN<<<dim3(nb2, 4), blk, 0, stream>>>(cnt, rpAll, bucketSum, n, nb2);
    scanB<<<4, blk, 0, stream>>>(bucketSum, rpBucket, nb2);
    baseFix<<<dim3(nb2, 4), blk, 0, stream>>>(rpAll, cur, rpBucket, n, nb2, EH, ES);
    scatterE<<<dim3(binb, 4), blk, 0, stream>>>(hs0, hd0, ss0, sd0, hs1, hd1, ss1, sd1,
                                                EH, ES, cur, srcAll, n);

    // ---------------- Layer 0 ----------------
    aggregate_z<<<aggb, blk, 0, stream>>>((const uint4*)hb0, (const uint4*)db0,
                                          rpH0, srcH0, rpS0, srcS0, (uint4*)z, n);
    gemm_mfma_l0<<<gemmb0, blk, 0, stream>>>(z, Wb0, b0, hbar1, db1, z, n);

    // ---------------- Layer 1 ----------------
    aggregate_z<<<aggb, blk, 0, stream>>>((const uint4*)hb1, (const uint4*)db1,
                                          rpH1, srcH1, rpS1, srcS1, (uint4*)z, n);
    gemm_mfma<3><<<gemmb1, dim3(128), 0, stream>>>(z, Wb1, b1, (float*)d_out, n, 47);
}

// Round 7
// 322.758 us; speedup vs baseline: 1.2245x; 1.2245x over previous
//
#include <hip/hip_runtime.h>

// N=50000, D=128 (both layers), K=256, EH=500000, ES=250000.
#define D_FEAT 128
#define K_DIM  256
#define EPB_B 1024  // edges per histB/binA block: 4x more blocks than 4096 -> ~30 waves/CU
#define PADL 136   // LDS leading dim (ushorts) for the 32x128 epilogue tile; 272B row, 16B-aligned

// ---- fragment-major layouts (eliminates 64-line address divergence in GEMMs) ----
// Wb (layer L, NT tiles): slot ((k0*NT + T)*64 + lane) * 8 shorts
//   = W[T*16 + (lane&15)][k0*32 + (lane>>4)*8 .. +8]
// z  (A operand):        slot ((G*8 + k0)*64 + lane) * 8 shorts,  G = row group of 16
//   = z_row[G*16 + (lane&15)][k0*32 + (lane>>4)*8 .. +8]

typedef __attribute__((ext_vector_type(8))) short bf16x8;
typedef __attribute__((ext_vector_type(4))) float f32x4;
typedef __attribute__((ext_vector_type(2))) float f32x2;

__device__ __forceinline__ unsigned short f2b(float f) {
    union { float f; unsigned u; } cv; cv.f = f;
    return (unsigned short)((cv.u + 0x7fffu + ((cv.u >> 16) & 1u)) >> 16);
}

__device__ __forceinline__ unsigned pack2(float lo, float hi) {
    return (unsigned)f2b(lo) | ((unsigned)f2b(hi) << 16);
}

__device__ __forceinline__ uint4 pack8(float4 a, float4 b) {
    return make_uint4(pack2(a.x, a.y), pack2(a.z, a.w), pack2(b.x, b.y), pack2(b.z, b.w));
}

// unpack one u32 (2 bf16) into a packed float2 -> enables v_pk_add_f32 accumulation
__device__ __forceinline__ f32x2 up2(unsigned u) {
    union { unsigned u; float f; } lo, hi;
    lo.u = u << 16; hi.u = u & 0xffff0000u;
    f32x2 r; r.x = lo.f; r.y = hi.f; return r;
}

__device__ __forceinline__ void addu4p(f32x2* a, uint4 v) {
    a[0] += up2(v.x); a[1] += up2(v.y); a[2] += up2(v.z); a[3] += up2(v.w);
}

__device__ __forceinline__ float blo(unsigned u) { union { unsigned u; float f; } c; c.u = u << 16; return c.f; }
__device__ __forceinline__ float bhi(unsigned u) { union { unsigned u; float f; } c; c.u = u & 0xffff0000u; return c.f; }

// edge-array offset within the concatenated [H0|S0|H1|S1] space
__device__ __forceinline__ long yoff(int y, int EH, int ES) {
    return (long)((y + 1) >> 1) * EH + (long)(y >> 1) * ES;
}

// ---------------- bucket-level CSR build (both layers; y in 0..3) ----------------
// LDS-atomic histograms only -- per-node GLOBAL atomics measured 2-3x slower (r5).

__global__ __launch_bounds__(256)
void histB(const int* __restrict__ hd0, const int* __restrict__ sd0,
           const int* __restrict__ hd1, const int* __restrict__ sd1,
           int EH, int ES, int* __restrict__ bucketCnt, int nb2) {
    int y = blockIdx.y;
    const int* d = (y == 0) ? hd0 : (y == 1) ? sd0 : (y == 2) ? hd1 : sd1;
    int E = (y & 1) ? ES : EH;
    __shared__ int cnt[256];
    int t = threadIdx.x;
    cnt[t] = 0;
    __syncthreads();
    int i0 = blockIdx.x * EPB_B;
    #pragma unroll
    for (int j = 0; j < 4; ++j) {
        int i = i0 + j * 256 + t;
        if (i < E) atomicAdd(&cnt[d[i] >> 8], 1);
    }
    __syncthreads();
    if (t < nb2 && cnt[t] > 0) atomicAdd(&bucketCnt[y * nb2 + t], cnt[t]);
}

// Parallel exclusive scan of the 196 bucket counts per etype (one block per etype).
__global__ __launch_bounds__(256)
void scanBuckets(const int* __restrict__ bucketCnt, int* __restrict__ rpBucket,
                 int* __restrict__ bcur, int nb2) {
    int y = blockIdx.x;
    int t = threadIdx.x;
    __shared__ int sh[256];
    int c = (t < nb2) ? bucketCnt[y * nb2 + t] : 0;
    sh[t] = c;
    __syncthreads();
    for (int o = 1; o < 256; o <<= 1) {
        int x = (t >= o) ? sh[t - o] : 0;
        __syncthreads();
        sh[t] += x;
        __syncthreads();
    }
    int excl = t ? sh[t - 1] : 0;
    if (t < nb2) {
        rpBucket[y * (nb2 + 1) + t] = excl;
        bcur[y * nb2 + t] = excl;
    }
    if (t == 0) rpBucket[y * (nb2 + 1) + nb2] = sh[255];  // total = E
}

// Record: src (24 bits) | localDst (8 bits) << 24.
__global__ __launch_bounds__(256)
void binA(const int* __restrict__ hs0, const int* __restrict__ hd0,
          const int* __restrict__ ss0, const int* __restrict__ sd0,
          const int* __restrict__ hs1, const int* __restrict__ hd1,
          const int* __restrict__ ss1, const int* __restrict__ sd1,
          int EH, int ES, int* __restrict__ bcur, unsigned* __restrict__ recs,
          int nb2) {
    int y = blockIdx.y;
    const int* src = (y == 0) ? hs0 : (y == 1) ? ss0 : (y == 2) ? hs1 : ss1;
    const int* dst = (y == 0) ? hd0 : (y == 1) ? sd0 : (y == 2) ? hd1 : sd1;
    int E = (y & 1) ? ES : EH;
    unsigned* rb = recs + yoff(y, EH, ES);

    __shared__ int cnt[256];
    int t = threadIdx.x;
    cnt[t] = 0;
    __syncthreads();
    int i0 = blockIdx.x * EPB_B;
    #pragma unroll
    for (int j = 0; j < 4; ++j) {
        int i = i0 + j * 256 + t;
        if (i < E) atomicAdd(&cnt[dst[i] >> 8], 1);
    }
    __syncthreads();
    int c = cnt[t];
    __syncthreads();
    if (t < nb2 && c > 0) cnt[t] = atomicAdd(&bcur[y * nb2 + t], c);
    __syncthreads();
    #pragma unroll
    for (int j = 0; j < 4; ++j) {
        int i = i0 + j * 256 + t;
        if (i < E) {
            int dd = dst[i];
            int slot = atomicAdd(&cnt[dd >> 8], 1);
            rb[slot] = (unsigned)src[i] | ((unsigned)(dd & 255) << 24);
        }
    }
}

// 512 threads (8 waves): halves the serial per-bucket chunk count and doubles
// resident waves/CU (12 -> 24) for this latency-bound pass.
__global__ __launch_bounds__(512)
void placeB(const unsigned* __restrict__ recs, const int* __restrict__ rpBucket,
            int* __restrict__ rpAll, int* __restrict__ srcAll,
            int EH, int ES, int n, int nb2) {
    int y = blockIdx.y;
    int b = blockIdx.x;
    int E = (y & 1) ? ES : EH;
    int* rp = rpAll + (size_t)y * (n + 1);
    long off = yoff(y, EH, ES);
    const unsigned* rb = recs + off;
    int* sb = srcAll + off;
    int e0 = rpBucket[y * (nb2 + 1) + b];
    int e1 = rpBucket[y * (nb2 + 1) + b + 1];
    int nodeBase = b << 8;

    __shared__ int cnt[256];
    __shared__ int sh[256];
    int t = threadIdx.x;
    if (t < 256) cnt[t] = 0;
    __syncthreads();
    for (int e = e0 + t; e < e1; e += 512)
        atomicAdd(&cnt[rb[e] >> 24], 1);
    __syncthreads();
    if (t < 256) sh[t] = cnt[t];
    __syncthreads();
    for (int o = 1; o < 256; o <<= 1) {
        int x = (t >= o && t < 256) ? sh[t - o] : 0;
        __syncthreads();
        if (t < 256) sh[t] += x;
        __syncthreads();
    }
    if (t < 256) {
        int base = e0 + (t ? sh[t - 1] : 0);
        if (nodeBase + t < n) rp[nodeBase + t] = base;
        cnt[t] = base;
    }
    if (b == 0 && t == 0) rp[n] = E;
    __syncthreads();
    for (int e = e0 + t; e < e1; e += 512) {
        unsigned r = rb[e];
        int p = atomicAdd(&cnt[r >> 24], 1);
        sb[p] = (int)(r & 0x00FFFFFFu);
    }
}

// ---------------- upfront bf16 prep ----------------
// hb0/db0/hb1 stay row-major (gather targets); z left half written fragment-major.
__global__ __launch_bounds__(256)
void prep_static(const float4* __restrict__ x, const float4* __restrict__ hbar0,
                 const float4* __restrict__ hbar1,
                 uint4* __restrict__ hb0, uint4* __restrict__ db0,
                 uint4* __restrict__ hb1, uint4* __restrict__ z, int n16) {
    int i = blockIdx.x * 256 + threadIdx.x;
    if (i >= n16) return;
    float4 xa = x[i * 2],     xb = x[i * 2 + 1];
    float4 ba = hbar0[i * 2], bb = hbar0[i * 2 + 1];
    float4 ca = hbar1[i * 2], cb = hbar1[i * 2 + 1];
    hb0[i] = pack8(ba, bb);
    db0[i] = pack8(make_float4(xa.x - ba.x, xa.y - ba.y, xa.z - ba.z, xa.w - ba.w),
                   make_float4(xb.x - bb.x, xb.y - bb.y, xb.z - bb.z, xb.w - bb.w));
    hb1[i] = pack8(ca, cb);
    int g = i >> 4, seg = i & 15;
    int G = g >> 4, r = g & 15, k0 = seg >> 2, kq = seg & 3;
    z[((size_t)G * 8 + k0) * 64 + kq * 16 + r] = pack8(xa, xb);   // fragment-major
}

// Weights -> fragment-major bf16. Layer0: 8 k0 x 8 T x 64 lanes; layer1: 8 x 3 x 64.
__global__ __launch_bounds__(256)
void conv_weights(const float* __restrict__ W0, unsigned short* __restrict__ WbF0,
                  const float* __restrict__ W1, unsigned short* __restrict__ WbF1) {
    int i = blockIdx.x * 256 + threadIdx.x;
    if (i < 4096) {
        int k0 = i >> 9, T = (i >> 6) & 7, lane = i & 63;
        int col = T * 16 + (lane & 15);
        int kb = k0 * 32 + (lane >> 4) * 8;
        const float* src = W0 + (size_t)col * 256 + kb;
        unsigned short* dst = WbF0 + (size_t)i * 8;
        #pragma unroll
        for (int e = 0; e < 8; ++e) dst[e] = f2b(src[e]);
    }
    if (i < 1536) {
        int k0 = i / 192, rem = i % 192;
        int T = rem >> 6, lane = rem & 63;
        int col = T * 16 + (lane & 15);
        int kb = k0 * 32 + (lane >> 4) * 8;
        unsigned short* dst = WbF1 + (size_t)i * 8;
        #pragma unroll
        for (int e = 0; e < 8; ++e)
            dst[e] = (col < 47) ? f2b(W1[(size_t)col * 256 + kb + e]) : (unsigned short)0;
    }
}

// ---------------- aggregation: one full wave per node ----------------
// 64 lanes = 4 edges (j = lane>>4) x 16 feature-segments (l = lane&15, 16B each).
// H and S edge streams interleaved in one pipeline; src indices prefetched one
// iteration ahead; packed f32x2 accumulation. (Proven 44 us / dispatch; request-queue
// bound on random 256B gathers -- MLP increases beyond this are neutral, r3/r4.)
__global__ __launch_bounds__(256)
void aggregate_z(const uint4* __restrict__ HB, const uint4* __restrict__ DB,
                 const int* __restrict__ rpH, const int* __restrict__ srcH,
                 const int* __restrict__ rpS, const int* __restrict__ srcS,
                 uint4* __restrict__ z, int n) {
    int g = blockIdx.x * 4 + (threadIdx.x >> 6);
    if (g >= n) return;
    int lane = threadIdx.x & 63;
    int j = lane >> 4, l = lane & 15;

    int hb_ = rpH[g], he = rpH[g + 1];
    int sb  = rpS[g], se = rpS[g + 1];
    int dH = he - hb_, dS = se - sb;
    int nIt = max((dH + 7) >> 3, (dS + 7) >> 3);

    f32x2 a[4] = {};
    f32x2 d[4] = {};

    int iH1 = hb_ + j, iH2 = hb_ + 4 + j;
    int iS1 = sb + j,  iS2 = sb + 4 + j;
    int sH1 = 0, sH2 = 0, sS1 = 0, sS2 = 0;
    if (iH1 < he) sH1 = srcH[iH1];
    if (iH2 < he) sH2 = srcH[iH2];
    if (iS1 < se) sS1 = srcS[iS1];
    if (iS2 < se) sS2 = srcS[iS2];

    for (int it = 0; it < nIt; ++it) {
        uint4 h1 = make_uint4(0, 0, 0, 0), h2 = make_uint4(0, 0, 0, 0);
        uint4 s1 = make_uint4(0, 0, 0, 0), s2 = make_uint4(0, 0, 0, 0);
        if (iH1 < he) h1 = HB[(size_t)sH1 * 16 + l];
        if (iH2 < he) h2 = HB[(size_t)sH2 * 16 + l];
        if (iS1 < se) s1 = DB[(size_t)sS1 * 16 + l];
        if (iS2 < se) s2 = DB[(size_t)sS2 * 16 + l];
        iH1 += 8; iH2 += 8; iS1 += 8; iS2 += 8;
        if (iH1 < he) sH1 = srcH[iH1];
        if (iH2 < he) sH2 = srcH[iH2];
        if (iS1 < se) sS1 = srcS[iS1];
        if (iS2 < se) sS2 = srcS[iS2];
        addu4p(a, h1); addu4p(a, h2);
        addu4p(d, s1); addu4p(d, s2);
    }

    float rH = 1.0f / fmaxf((float)dH, 1.0f);
    float rS = 1.0f / fmaxf((float)dS, 1.0f);
    float s[8];
    #pragma unroll
    for (int i = 0; i < 4; ++i) {
        float v0 = a[i].x * rH + d[i].x * rS;
        float v1 = a[i].y * rH + d[i].y * rS;
        v0 += __shfl_xor(v0, 16);
        v0 += __shfl_xor(v0, 32);
        v1 += __shfl_xor(v1, 16);
        v1 += __shfl_xor(v1, 32);
        s[2 * i] = v0;
        s[2 * i + 1] = v1;
    }
    if (j == 0) {
        // lane l holds k = 128 + l*8 .. +8  ->  fragment slot
        uint4 rv = make_uint4(pack2(s[0], s[1]), pack2(s[2], s[3]),
                              pack2(s[4], s[5]), pack2(s[6], s[7]));
        size_t slot = ((size_t)(g >> 4) * 8 + 4 + (l >> 2)) * 64 + (l & 3) * 16 + (g & 15);
        z[slot] = rv;
    }
}

// ---------------- MFMA GEMM layer 0: fused epilogue (LDS-transposed) ----------------
// Block: 256 thr = 4 waves; 32 rows/block. Wave (rt,ch): rows rt*16..+16, cols ch*64..+64.
// A and B read from fragment-major buffers: every load = contiguous 1KiB per wave.
__global__ __launch_bounds__(256, 2)
void gemm_mfma_l0(const unsigned short* __restrict__ Z, const unsigned short* __restrict__ Wb,
                  const float* __restrict__ bias, const float* __restrict__ hbar1,
                  unsigned short* __restrict__ db1, unsigned short* __restrict__ zl, int n) {
    __shared__ unsigned short hl[32 * PADL];
    int tid  = threadIdx.x;
    int wave = tid >> 6;
    int lane = tid & 63;
    int rt = wave >> 1;                 // row tile 0..1
    int ch = wave & 1;                  // col half 0..1
    int m0 = blockIdx.x * 32;
    int cl = lane & 15;
    int kq = lane >> 4;

    const short* Af = (const short*)Z;
    const short* Bf = (const short*)Wb;
    size_t G = (size_t)(m0 >> 4) + rt;

    // A row-slice: 8 coalesced fragment loads (32 VGPR, all in flight)
    bf16x8 aF[8];
    #pragma unroll
    for (int k0 = 0; k0 < 8; ++k0)
        aF[k0] = *(const bf16x8*)(Af + ((G * 8 + k0) * 64 + lane) * 8);

    f32x4 acc[4] = {};
    bf16x8 bF[2][4];
    #pragma unroll
    for (int t = 0; t < 4; ++t)
        bF[0][t] = *(const bf16x8*)(Bf + ((size_t)((0 * 8 + ch * 4 + t)) * 64 + lane) * 8);

    #pragma unroll
    for (int k0 = 0; k0 < 8; ++k0) {
        int cur = k0 & 1, nxt = cur ^ 1;
        if (k0 < 7) {
            #pragma unroll
            for (int t = 0; t < 4; ++t)
                bF[nxt][t] = *(const bf16x8*)(Bf + ((size_t)(((k0 + 1) * 8 + ch * 4 + t)) * 64 + lane) * 8);
        }
        #pragma unroll
        for (int t = 0; t < 4; ++t)
            acc[t] = __builtin_amdgcn_mfma_f32_16x16x32_bf16(aF[k0], bF[cur][t], acc[t], 0, 0, 0);
    }

    // stage h = relu(acc + bias) into LDS tile [32][PADL] (bf16)
    #pragma unroll
    for (int t = 0; t < 4; ++t) {
        int c = ch * 64 + t * 16 + cl;
        float bv = bias[c];
        #pragma unroll
        for (int r = 0; r < 4; ++r) {
            int row = rt * 16 + kq * 4 + r;
            hl[row * PADL + c] = f2b(fmaxf(acc[t][r] + bv, 0.0f));
        }
    }
    __syncthreads();

    // zl (layer-1 A operand) written FRAGMENT-MAJOR: 512 slots of 16B, coalesced.
    #pragma unroll
    for (int s = 0; s < 2; ++s) {
        int ls = tid + s * 256;
        int gi = ls >> 8, k0 = (ls >> 6) & 3, ln = ls & 63;
        int rl = gi * 16 + (ln & 15);
        int col = k0 * 32 + (ln >> 4) * 8;
        int m = m0 + rl;
        if (m < n) {
            uint4 v = *(const uint4*)(hl + rl * PADL + col);
            ((uint4*)zl)[((size_t)(m0 >> 4) + gi) * 8 * 64 + (size_t)k0 * 64 + ln] = v;
        }
    }

    // db1 = bf16(h - hbar1), row-major (gather target), coalesced
    int row  = tid >> 3;
    int col  = (tid & 7) * 16;
    int m    = m0 + row;
    if (m < n) {
        const uint4* hr = (const uint4*)(hl + row * PADL + col);
        uint4 v0 = hr[0];
        uint4 v1 = hr[1];
        const float4* hb = (const float4*)(hbar1 + (size_t)m * 128 + col);
        float4 h0 = hb[0], h1 = hb[1], h2 = hb[2], h3 = hb[3];
        uint4 d0, d1;
        d0.x = pack2(blo(v0.x) - h0.x, bhi(v0.x) - h0.y);
        d0.y = pack2(blo(v0.y) - h0.z, bhi(v0.y) - h0.w);
        d0.z = pack2(blo(v0.z) - h1.x, bhi(v0.z) - h1.y);
        d0.w = pack2(blo(v0.w) - h1.z, bhi(v0.w) - h1.w);
        d1.x = pack2(blo(v1.x) - h2.x, bhi(v1.x) - h2.y);
        d1.y = pack2(blo(v1.y) - h2.z, bhi(v1.y) - h2.w);
        d1.z = pack2(blo(v1.z) - h3.x, bhi(v1.z) - h3.y);
        d1.w = pack2(blo(v1.w) - h3.z, bhi(v1.w) - h3.w);
        uint4* dp = (uint4*)(db1 + (size_t)m * 128 + col);
        dp[0] = d0;
        dp[1] = d1;
    }
}

// ---------------- MFMA GEMM layer 1 -> f32 out ----------------
// 128-thread blocks (2 waves, 32 rows); fragment-major A and B.
template<int NT>
__global__ __launch_bounds__(128, 2)
void gemm_mfma(const unsigned short* __restrict__ Z, const unsigned short* __restrict__ Wb,
               const float* __restrict__ bias, float* __restrict__ out, int n, int COLS) {
    int wave = threadIdx.x >> 6;
    int lane = threadIdx.x & 63;
    int m0 = blockIdx.x * 32 + wave * 16;
    int cl = lane & 15;
    int kq = lane >> 4;

    const short* Af = (const short*)Z;
    const short* Bf = (const short*)Wb;
    size_t G = (size_t)(m0 >> 4);

    bf16x8 aF[8];
    #pragma unroll
    for (int k0 = 0; k0 < 8; ++k0)
        aF[k0] = *(const bf16x8*)(Af + ((G * 8 + k0) * 64 + lane) * 8);

    f32x4 acc[NT] = {};
    bf16x8 bF[2][NT];
    #pragma unroll
    for (int t = 0; t < NT; ++t)
        bF[0][t] = *(const bf16x8*)(Bf + ((size_t)(0 * NT + t) * 64 + lane) * 8);

    #pragma unroll
    for (int k0 = 0; k0 < 8; ++k0) {
        int cur = k0 & 1, nxt = cur ^ 1;
        if (k0 < 7) {
            #pragma unroll
            for (int t = 0; t < NT; ++t)
                bF[nxt][t] = *(const bf16x8*)(Bf + ((size_t)((k0 + 1) * NT + t) * 64 + lane) * 8);
        }
        #pragma unroll
        for (int t = 0; t < NT; ++t)
            acc[t] = __builtin_amdgcn_mfma_f32_16x16x32_bf16(aF[k0], bF[cur][t], acc[t], 0, 0, 0);
    }

    int rg = kq * 4;
    #pragma unroll
    for (int t = 0; t < NT; ++t) {
        int c = t * 16 + cl;
        if (c >= COLS) continue;
        float bv = bias[c];
        #pragma unroll
        for (int r = 0; r < 4; ++r) {
            int m = m0 + rg + r;
            if (m < n) out[(size_t)m * COLS + c] = fmaxf(acc[t][r] + bv, 0.f);
        }
    }
}

extern "C" void kernel_launch(void* const* d_in, const int* in_sizes, int n_in,
                              void* d_out, int out_size, void* d_ws, size_t ws_size,
                              hipStream_t stream) {
    const float* x     = (const float*)d_in[0];
    const float* hbar0 = (const float*)d_in[1];
    const float* hbar1 = (const float*)d_in[2];
    const float* W0    = (const float*)d_in[3];
    const float* b0    = (const float*)d_in[4];
    const float* W1    = (const float*)d_in[5];
    const float* b1    = (const float*)d_in[6];
    const int* hs0 = (const int*)d_in[7];
    const int* hd0 = (const int*)d_in[8];
    const int* ss0 = (const int*)d_in[9];
    const int* sd0 = (const int*)d_in[10];
    const int* hs1 = (const int*)d_in[11];
    const int* hd1 = (const int*)d_in[12];
    const int* ss1 = (const int*)d_in[13];
    const int* sd1 = (const int*)d_in[14];

    const int n   = in_sizes[0] / D_FEAT;   // 50000
    const int EH  = in_sizes[7];            // 500000
    const int ES  = in_sizes[9];            // 250000
    const int nb2 = (n + 255) / 256;        // 196 dst buckets per etype

    // ---- workspace layout ----
    int* bucketCnt = (int*)d_ws;                       // 4*nb2
    int* rpBucket  = bucketCnt + 4 * nb2;              // 4*(nb2+1)
    int* bcur      = rpBucket + 4 * (nb2 + 1);         // 4*nb2
    int* rpAll     = bcur + 4 * nb2;                   // 4*(n+1)
    int* srcAll    = rpAll + 4 * (size_t)(n + 1);      // 2EH+2ES
    unsigned* recs = (unsigned*)(srcAll + 2 * (size_t)EH + 2 * (size_t)ES); // 2EH+2ES
    size_t int_words = (size_t)12 * nb2 + 4 + 4 * (size_t)(n + 1)
                     + 4 * (size_t)EH + 4 * (size_t)ES;
    int_words = (int_words + 3) & ~(size_t)3;                          // 16 B align
    unsigned short* hb0 = (unsigned short*)((int*)d_ws + int_words);   // n*128 bf16
    unsigned short* db0 = hb0 + (size_t)n * D_FEAT;                    // n*128 bf16
    unsigned short* hb1 = db0 + (size_t)n * D_FEAT;                    // n*128 bf16
    unsigned short* db1 = hb1 + (size_t)n * D_FEAT;                    // n*128 bf16
    unsigned short* z   = db1 + (size_t)n * D_FEAT;                    // n*256 bf16 (+1 pad group)
    unsigned short* Wb0 = z + (size_t)n * K_DIM + 4096;                // 128*256 (pad: tail group reads)
    unsigned short* Wb1 = Wb0 + 128 * 256;                             // 64*256

    const int* rpH0 = rpAll;
    const int* rpS0 = rpAll + (size_t)(n + 1);
    const int* rpH1 = rpAll + 2 * (size_t)(n + 1);
    const int* rpS1 = rpAll + 3 * (size_t)(n + 1);
    int* srcH0 = srcAll;
    int* srcS0 = srcAll + (size_t)EH;
    int* srcH1 = srcAll + (size_t)EH + ES;
    int* srcS1 = srcAll + 2 * (size_t)EH + ES;

    dim3 blk(256);
    int binb  = (EH + EPB_B - 1) / EPB_B;   // 489 blocks/etype -> ~30 waves/CU
    int prepb = ((n * 16) + 255) / 256;
    int aggb  = (n + 3) / 4;
    int gemmb0 = (n + 31) / 32;   // 32 rows per block (layer-0 GEMM)
    int gemmb1 = (n + 31) / 32;   // 32 rows per block (layer-1 GEMM, 128 thr)

    // ---- CSR build for BOTH layers + static prep ----
    hipMemsetAsync(bucketCnt, 0, 4 * (size_t)nb2 * sizeof(int), stream);
    conv_weights<<<16, blk, 0, stream>>>(W0, Wb0, W1, Wb1);
    histB<<<dim3(binb, 4), blk, 0, stream>>>(hd0, sd0, hd1, sd1, EH, ES, bucketCnt, nb2);
    scanBuckets<<<4, blk, 0, stream>>>(bucketCnt, rpBucket, bcur, nb2);
    binA<<<dim3(binb, 4), blk, 0, stream>>>(hs0, hd0, ss0, sd0, hs1, hd1, ss1, sd1,
                                            EH, ES, bcur, recs, nb2);
    placeB<<<dim3(nb2, 4), dim3(512), 0, stream>>>(recs, rpBucket, rpAll, srcAll, EH, ES, n, nb2);
    prep_static<<<prepb, blk, 0, stream>>>((const float4*)x, (const float4*)hbar0,
                                           (const float4*)hbar1, (uint4*)hb0, (uint4*)db0,
                                           (uint4*)hb1, (uint4*)z, n * 16);

    // ---------------- Layer 0 ----------------
    aggregate_z<<<aggb, blk, 0, stream>>>((const uint4*)hb0, (const uint4*)db0,
                                          rpH0, srcH0, rpS0, srcS0, (uint4*)z, n);
    gemm_mfma_l0<<<gemmb0, blk, 0, stream>>>(z, Wb0, b0, hbar1, db1, z, n);

    // ---------------- Layer 1 ----------------
    aggregate_z<<<aggb, blk, 0, stream>>>((const uint4*)hb1, (const uint4*)db1,
                                          rpH1, srcH1, rpS1, srcS1, (uint4*)z, n);
    gemm_mfma<3><<<gemmb1, dim3(128), 0, stream>>>(z, Wb1, b1, (float*)d_out, n, 47);
}

// Round 8
// 291.945 us; speedup vs baseline: 1.3537x; 1.1055x over previous
//
#include <hip/hip_runtime.h>

// N=50000, D=128 (both layers), K=256, EH=500000, ES=250000.
#define D_FEAT 128
#define K_DIM  256
#define EPB 4096   // edges per histB/binA block (round-6 showed smaller is WORSE)
#define PADL 136   // LDS leading dim (ushorts) for the 32x128 epilogue tile
#define PB_CAP 4096  // LDS record cache per placeB bucket (30-sigma above mean 2560)

// ---- fragment-major layouts (eliminates 64-line address divergence in GEMMs) ----
// Wb (layer L, NT tiles): slot ((k0*NT + T)*64 + lane) * 8 shorts
// z  (A operand):        slot ((G*8 + k0)*64 + lane) * 8 shorts,  G = row group of 16

typedef __attribute__((ext_vector_type(8))) short bf16x8;
typedef __attribute__((ext_vector_type(4))) float f32x4;
typedef __attribute__((ext_vector_type(2))) float f32x2;

__device__ __forceinline__ unsigned short f2b(float f) {
    union { float f; unsigned u; } cv; cv.f = f;
    return (unsigned short)((cv.u + 0x7fffu + ((cv.u >> 16) & 1u)) >> 16);
}

__device__ __forceinline__ unsigned pack2(float lo, float hi) {
    return (unsigned)f2b(lo) | ((unsigned)f2b(hi) << 16);
}

__device__ __forceinline__ uint4 pack8(float4 a, float4 b) {
    return make_uint4(pack2(a.x, a.y), pack2(a.z, a.w), pack2(b.x, b.y), pack2(b.z, b.w));
}

__device__ __forceinline__ f32x2 up2(unsigned u) {
    union { unsigned u; float f; } lo, hi;
    lo.u = u << 16; hi.u = u & 0xffff0000u;
    f32x2 r; r.x = lo.f; r.y = hi.f; return r;
}

__device__ __forceinline__ void addu4p(f32x2* a, uint4 v) {
    a[0] += up2(v.x); a[1] += up2(v.y); a[2] += up2(v.z); a[3] += up2(v.w);
}

__device__ __forceinline__ float blo(unsigned u) { union { unsigned u; float f; } c; c.u = u << 16; return c.f; }
__device__ __forceinline__ float bhi(unsigned u) { union { unsigned u; float f; } c; c.u = u & 0xffff0000u; return c.f; }

// edge-array offset within the concatenated [H0|S0|H1|S1] space
__device__ __forceinline__ long yoff(int y, int EH, int ES) {
    return (long)((y + 1) >> 1) * EH + (long)(y >> 1) * ES;
}

// ---------------- bucket-level CSR build (both layers; y in 0..3) ----------------
// LDS-atomic histograms only -- per-node GLOBAL atomics measured 2-3x slower (r5).
// EPB=4096 / 256-thr placeB proven best (r6: more blocks / wider blocks regressed).

__global__ __launch_bounds__(256)
void histB(const int* __restrict__ hd0, const int* __restrict__ sd0,
           const int* __restrict__ hd1, const int* __restrict__ sd1,
           int EH, int ES, int* __restrict__ bucketCnt, int nb2) {
    int y = blockIdx.y;
    const int* d = (y == 0) ? hd0 : (y == 1) ? sd0 : (y == 2) ? hd1 : sd1;
    int E = (y & 1) ? ES : EH;
    __shared__ int cnt[256];
    int t = threadIdx.x;
    cnt[t] = 0;
    __syncthreads();
    int i0 = blockIdx.x * EPB;
    #pragma unroll
    for (int j = 0; j < 16; ++j) {
        int i = i0 + j * 256 + t;
        if (i < E) atomicAdd(&cnt[d[i] >> 8], 1);
    }
    __syncthreads();
    if (t < nb2 && cnt[t] > 0) atomicAdd(&bucketCnt[y * nb2 + t], cnt[t]);
}

// Parallel exclusive scan of the 196 bucket counts per etype (one block per etype).
__global__ __launch_bounds__(256)
void scanBuckets(const int* __restrict__ bucketCnt, int* __restrict__ rpBucket,
                 int* __restrict__ bcur, int nb2) {
    int y = blockIdx.x;
    int t = threadIdx.x;
    __shared__ int sh[256];
    int c = (t < nb2) ? bucketCnt[y * nb2 + t] : 0;
    sh[t] = c;
    __syncthreads();
    for (int o = 1; o < 256; o <<= 1) {
        int x = (t >= o) ? sh[t - o] : 0;
        __syncthreads();
        sh[t] += x;
        __syncthreads();
    }
    int excl = t ? sh[t - 1] : 0;
    if (t < nb2) {
        rpBucket[y * (nb2 + 1) + t] = excl;
        bcur[y * nb2 + t] = excl;
    }
    if (t == 0) rpBucket[y * (nb2 + 1) + nb2] = sh[255];  // total = E
}

// ---------------- fused binA + prep_static + conv_weights ----------------
// Blocks [0, 4*binb): binA record scatter (latency/LDS-atomic bound).
// Blocks [4*binb, +prepb): bf16 prep (pure streaming, BW-bound).
// Blocks [.., +16): weight conversion.
// Independent work; complementary bottlenecks overlap instead of serializing.
__global__ __launch_bounds__(256)
void binPrep(const int* __restrict__ hs0, const int* __restrict__ hd0,
             const int* __restrict__ ss0, const int* __restrict__ sd0,
             const int* __restrict__ hs1, const int* __restrict__ hd1,
             const int* __restrict__ ss1, const int* __restrict__ sd1,
             int EH, int ES, int* __restrict__ bcur, unsigned* __restrict__ recs,
             int nb2, int binb,
             const float4* __restrict__ x, const float4* __restrict__ hbar0,
             const float4* __restrict__ hbar1,
             uint4* __restrict__ hb0, uint4* __restrict__ db0,
             uint4* __restrict__ hb1, uint4* __restrict__ z, int n16, int prepb,
             const float* __restrict__ W0, unsigned short* __restrict__ WbF0,
             const float* __restrict__ W1, unsigned short* __restrict__ WbF1) {
    __shared__ int cnt[256];
    int bid = blockIdx.x;
    int t = threadIdx.x;

    if (bid < 4 * binb) {
        // ---- binA: record scatter (EPB edges per block) ----
        int y = bid / binb, c = bid % binb;
        const int* src = (y == 0) ? hs0 : (y == 1) ? ss0 : (y == 2) ? hs1 : ss1;
        const int* dst = (y == 0) ? hd0 : (y == 1) ? sd0 : (y == 2) ? hd1 : sd1;
        int E = (y & 1) ? ES : EH;
        unsigned* rb = recs + yoff(y, EH, ES);

        cnt[t] = 0;
        __syncthreads();
        int i0 = c * EPB;
        #pragma unroll
        for (int j = 0; j < 16; ++j) {
            int i = i0 + j * 256 + t;
            if (i < E) atomicAdd(&cnt[dst[i] >> 8], 1);
        }
        __syncthreads();
        int cc = cnt[t];
        __syncthreads();
        if (t < nb2 && cc > 0) cnt[t] = atomicAdd(&bcur[y * nb2 + t], cc);
        __syncthreads();
        #pragma unroll
        for (int j = 0; j < 16; ++j) {
            int i = i0 + j * 256 + t;
            if (i < E) {
                int dd = dst[i];
                int slot = atomicAdd(&cnt[dd >> 8], 1);
                rb[slot] = (unsigned)src[i] | ((unsigned)(dd & 255) << 24);
            }
        }
    } else if (bid < 4 * binb + prepb) {
        // ---- prep_static: streaming bf16 prep ----
        int i = (bid - 4 * binb) * 256 + t;
        if (i >= n16) return;
        float4 xa = x[i * 2],     xb = x[i * 2 + 1];
        float4 ba = hbar0[i * 2], bb = hbar0[i * 2 + 1];
        float4 ca = hbar1[i * 2], cb = hbar1[i * 2 + 1];
        hb0[i] = pack8(ba, bb);
        db0[i] = pack8(make_float4(xa.x - ba.x, xa.y - ba.y, xa.z - ba.z, xa.w - ba.w),
                       make_float4(xb.x - bb.x, xb.y - bb.y, xb.z - bb.z, xb.w - bb.w));
        hb1[i] = pack8(ca, cb);
        int g = i >> 4, seg = i & 15;
        int G = g >> 4, r = g & 15, k0 = seg >> 2, kq = seg & 3;
        z[((size_t)G * 8 + k0) * 64 + kq * 16 + r] = pack8(xa, xb);   // fragment-major
    } else {
        // ---- conv_weights: fragment-major bf16 weights ----
        int i = (bid - 4 * binb - prepb) * 256 + t;
        if (i < 4096) {
            int k0 = i >> 9, T = (i >> 6) & 7, lane = i & 63;
            int col = T * 16 + (lane & 15);
            int kb = k0 * 32 + (lane >> 4) * 8;
            const float* src = W0 + (size_t)col * 256 + kb;
            unsigned short* dst = WbF0 + (size_t)i * 8;
            #pragma unroll
            for (int e = 0; e < 8; ++e) dst[e] = f2b(src[e]);
        }
        if (i < 1536) {
            int k0 = i / 192, rem = i % 192;
            int T = rem >> 6, lane = rem & 63;
            int col = T * 16 + (lane & 15);
            int kb = k0 * 32 + (lane >> 4) * 8;
            unsigned short* dst = WbF1 + (size_t)i * 8;
            #pragma unroll
            for (int e = 0; e < 8; ++e)
                dst[e] = (col < 47) ? f2b(W1[(size_t)col * 256 + kb + e]) : (unsigned short)0;
        }
    }
}

// ---------------- placeB: single-pass (records cached in LDS) ----------------
// Old version read the 6MB record array twice (count + scatter). A bucket's
// ~2560 records fit in a 16KB LDS cache; overflow (>4096, ~30 sigma) falls
// back to the global read, so correctness never depends on the cap.
__global__ __launch_bounds__(256)
void placeB(const unsigned* __restrict__ recs, const int* __restrict__ rpBucket,
            int* __restrict__ rpAll, int* __restrict__ srcAll,
            int EH, int ES, int n, int nb2) {
    int y = blockIdx.y;
    int b = blockIdx.x;
    int E = (y & 1) ? ES : EH;
    int* rp = rpAll + (size_t)y * (n + 1);
    long off = yoff(y, EH, ES);
    const unsigned* rb = recs + off;
    int* sb = srcAll + off;
    int e0 = rpBucket[y * (nb2 + 1) + b];
    int e1 = rpBucket[y * (nb2 + 1) + b + 1];
    int nodeBase = b << 8;
    int ne = e1 - e0;

    __shared__ unsigned eb[PB_CAP];
    __shared__ int cnt[256];
    __shared__ int sh[256];
    int t = threadIdx.x;
    cnt[t] = 0;
    __syncthreads();
    for (int e = t; e < ne; e += 256) {
        unsigned r = rb[e0 + e];
        if (e < PB_CAP) eb[e] = r;
        atomicAdd(&cnt[r >> 24], 1);
    }
    __syncthreads();
    sh[t] = cnt[t];
    __syncthreads();
    for (int o = 1; o < 256; o <<= 1) {
        int v = (t >= o) ? sh[t - o] : 0;
        __syncthreads();
        sh[t] += v;
        __syncthreads();
    }
    int base = e0 + (t ? sh[t - 1] : 0);
    if (nodeBase + t < n) rp[nodeBase + t] = base;
    if (b == 0 && t == 0) rp[n] = E;
    cnt[t] = base;
    __syncthreads();
    for (int e = t; e < ne; e += 256) {
        unsigned r = (e < PB_CAP) ? eb[e] : rb[e0 + e];
        int p = atomicAdd(&cnt[r >> 24], 1);
        sb[p] = (int)(r & 0x00FFFFFFu);
    }
}

// ---------------- aggregation: one full wave per node ----------------
// 64 lanes = 4 edges (j = lane>>4) x 16 feature-segments (l = lane&15, 16B each).
// Proven 43.2 us / dispatch; request-queue bound on random 256B gathers --
// more MLP (r3), co-resident streams (r4) both null/regressed.
__global__ __launch_bounds__(256)
void aggregate_z(const uint4* __restrict__ HB, const uint4* __restrict__ DB,
                 const int* __restrict__ rpH, const int* __restrict__ srcH,
                 const int* __restrict__ rpS, const int* __restrict__ srcS,
                 uint4* __restrict__ z, int n) {
    int g = blockIdx.x * 4 + (threadIdx.x >> 6);
    if (g >= n) return;
    int lane = threadIdx.x & 63;
    int j = lane >> 4, l = lane & 15;

    int hb_ = rpH[g], he = rpH[g + 1];
    int sb  = rpS[g], se = rpS[g + 1];
    int dH = he - hb_, dS = se - sb;
    int nIt = max((dH + 7) >> 3, (dS + 7) >> 3);

    f32x2 a[4] = {};
    f32x2 d[4] = {};

    int iH1 = hb_ + j, iH2 = hb_ + 4 + j;
    int iS1 = sb + j,  iS2 = sb + 4 + j;
    int sH1 = 0, sH2 = 0, sS1 = 0, sS2 = 0;
    if (iH1 < he) sH1 = srcH[iH1];
    if (iH2 < he) sH2 = srcH[iH2];
    if (iS1 < se) sS1 = srcS[iS1];
    if (iS2 < se) sS2 = srcS[iS2];

    for (int it = 0; it < nIt; ++it) {
        uint4 h1 = make_uint4(0, 0, 0, 0), h2 = make_uint4(0, 0, 0, 0);
        uint4 s1 = make_uint4(0, 0, 0, 0), s2 = make_uint4(0, 0, 0, 0);
        if (iH1 < he) h1 = HB[(size_t)sH1 * 16 + l];
        if (iH2 < he) h2 = HB[(size_t)sH2 * 16 + l];
        if (iS1 < se) s1 = DB[(size_t)sS1 * 16 + l];
        if (iS2 < se) s2 = DB[(size_t)sS2 * 16 + l];
        iH1 += 8; iH2 += 8; iS1 += 8; iS2 += 8;
        if (iH1 < he) sH1 = srcH[iH1];
        if (iH2 < he) sH2 = srcH[iH2];
        if (iS1 < se) sS1 = srcS[iS1];
        if (iS2 < se) sS2 = srcS[iS2];
        addu4p(a, h1); addu4p(a, h2);
        addu4p(d, s1); addu4p(d, s2);
    }

    float rH = 1.0f / fmaxf((float)dH, 1.0f);
    float rS = 1.0f / fmaxf((float)dS, 1.0f);
    float s[8];
    #pragma unroll
    for (int i = 0; i < 4; ++i) {
        float v0 = a[i].x * rH + d[i].x * rS;
        float v1 = a[i].y * rH + d[i].y * rS;
        v0 += __shfl_xor(v0, 16);
        v0 += __shfl_xor(v0, 32);
        v1 += __shfl_xor(v1, 16);
        v1 += __shfl_xor(v1, 32);
        s[2 * i] = v0;
        s[2 * i + 1] = v1;
    }
    if (j == 0) {
        // lane l holds k = 128 + l*8 .. +8  ->  fragment slot
        uint4 rv = make_uint4(pack2(s[0], s[1]), pack2(s[2], s[3]),
                              pack2(s[4], s[5]), pack2(s[6], s[7]));
        size_t slot = ((size_t)(g >> 4) * 8 + 4 + (l >> 2)) * 64 + (l & 3) * 16 + (g & 15);
        z[slot] = rv;
    }
}

// ---------------- MFMA GEMM layer 0: fused epilogue (LDS-transposed) ----------------
__global__ __launch_bounds__(256, 2)
void gemm_mfma_l0(const unsigned short* __restrict__ Z, const unsigned short* __restrict__ Wb,
                  const float* __restrict__ bias, const float* __restrict__ hbar1,
                  unsigned short* __restrict__ db1, unsigned short* __restrict__ zl, int n) {
    __shared__ unsigned short hl[32 * PADL];
    int tid  = threadIdx.x;
    int wave = tid >> 6;
    int lane = tid & 63;
    int rt = wave >> 1;                 // row tile 0..1
    int ch = wave & 1;                  // col half 0..1
    int m0 = blockIdx.x * 32;
    int cl = lane & 15;
    int kq = lane >> 4;

    const short* Af = (const short*)Z;
    const short* Bf = (const short*)Wb;
    size_t G = (size_t)(m0 >> 4) + rt;

    // A row-slice: 8 coalesced fragment loads (32 VGPR, all in flight)
    bf16x8 aF[8];
    #pragma unroll
    for (int k0 = 0; k0 < 8; ++k0)
        aF[k0] = *(const bf16x8*)(Af + ((G * 8 + k0) * 64 + lane) * 8);

    f32x4 acc[4] = {};
    bf16x8 bF[2][4];
    #pragma unroll
    for (int t = 0; t < 4; ++t)
        bF[0][t] = *(const bf16x8*)(Bf + ((size_t)((0 * 8 + ch * 4 + t)) * 64 + lane) * 8);

    #pragma unroll
    for (int k0 = 0; k0 < 8; ++k0) {
        int cur = k0 & 1, nxt = cur ^ 1;
        if (k0 < 7) {
            #pragma unroll
            for (int t = 0; t < 4; ++t)
                bF[nxt][t] = *(const bf16x8*)(Bf + ((size_t)(((k0 + 1) * 8 + ch * 4 + t)) * 64 + lane) * 8);
        }
        #pragma unroll
        for (int t = 0; t < 4; ++t)
            acc[t] = __builtin_amdgcn_mfma_f32_16x16x32_bf16(aF[k0], bF[cur][t], acc[t], 0, 0, 0);
    }

    // stage h = relu(acc + bias) into LDS tile [32][PADL] (bf16)
    #pragma unroll
    for (int t = 0; t < 4; ++t) {
        int c = ch * 64 + t * 16 + cl;
        float bv = bias[c];
        #pragma unroll
        for (int r = 0; r < 4; ++r) {
            int row = rt * 16 + kq * 4 + r;
            hl[row * PADL + c] = f2b(fmaxf(acc[t][r] + bv, 0.0f));
        }
    }
    __syncthreads();

    // zl (layer-1 A operand) written FRAGMENT-MAJOR: 512 slots of 16B, coalesced.
    #pragma unroll
    for (int s = 0; s < 2; ++s) {
        int ls = tid + s * 256;
        int gi = ls >> 8, k0 = (ls >> 6) & 3, ln = ls & 63;
        int rl = gi * 16 + (ln & 15);
        int col = k0 * 32 + (ln >> 4) * 8;
        int m = m0 + rl;
        if (m < n) {
            uint4 v = *(const uint4*)(hl + rl * PADL + col);
            ((uint4*)zl)[((size_t)(m0 >> 4) + gi) * 8 * 64 + (size_t)k0 * 64 + ln] = v;
        }
    }

    // db1 = bf16(h - hbar1), row-major (gather target), coalesced
    int row  = tid >> 3;
    int col  = (tid & 7) * 16;
    int m    = m0 + row;
    if (m < n) {
        const uint4* hr = (const uint4*)(hl + row * PADL + col);
        uint4 v0 = hr[0];
        uint4 v1 = hr[1];
        const float4* hb = (const float4*)(hbar1 + (size_t)m * 128 + col);
        float4 h0 = hb[0], h1 = hb[1], h2 = hb[2], h3 = hb[3];
        uint4 d0, d1;
        d0.x = pack2(blo(v0.x) - h0.x, bhi(v0.x) - h0.y);
        d0.y = pack2(blo(v0.y) - h0.z, bhi(v0.y) - h0.w);
        d0.z = pack2(blo(v0.z) - h1.x, bhi(v0.z) - h1.y);
        d0.w = pack2(blo(v0.w) - h1.z, bhi(v0.w) - h1.w);
        d1.x = pack2(blo(v1.x) - h2.x, bhi(v1.x) - h2.y);
        d1.y = pack2(blo(v1.y) - h2.z, bhi(v1.y) - h2.w);
        d1.z = pack2(blo(v1.z) - h3.x, bhi(v1.z) - h3.y);
        d1.w = pack2(blo(v1.w) - h3.z, bhi(v1.w) - h3.w);
        uint4* dp = (uint4*)(db1 + (size_t)m * 128 + col);
        dp[0] = d0;
        dp[1] = d1;
    }
}

// ---------------- MFMA GEMM layer 1 -> f32 out ----------------
template<int NT>
__global__ __launch_bounds__(128, 2)
void gemm_mfma(const unsigned short* __restrict__ Z, const unsigned short* __restrict__ Wb,
               const float* __restrict__ bias, float* __restrict__ out, int n, int COLS) {
    int wave = threadIdx.x >> 6;
    int lane = threadIdx.x & 63;
    int m0 = blockIdx.x * 32 + wave * 16;
    int cl = lane & 15;
    int kq = lane >> 4;

    const short* Af = (const short*)Z;
    const short* Bf = (const short*)Wb;
    size_t G = (size_t)(m0 >> 4);

    bf16x8 aF[8];
    #pragma unroll
    for (int k0 = 0; k0 < 8; ++k0)
        aF[k0] = *(const bf16x8*)(Af + ((G * 8 + k0) * 64 + lane) * 8);

    f32x4 acc[NT] = {};
    bf16x8 bF[2][NT];
    #pragma unroll
    for (int t = 0; t < NT; ++t)
        bF[0][t] = *(const bf16x8*)(Bf + ((size_t)(0 * NT + t) * 64 + lane) * 8);

    #pragma unroll
    for (int k0 = 0; k0 < 8; ++k0) {
        int cur = k0 & 1, nxt = cur ^ 1;
        if (k0 < 7) {
            #pragma unroll
            for (int t = 0; t < NT; ++t)
                bF[nxt][t] = *(const bf16x8*)(Bf + ((size_t)((k0 + 1) * NT + t) * 64 + lane) * 8);
        }
        #pragma unroll
        for (int t = 0; t < NT; ++t)
            acc[t] = __builtin_amdgcn_mfma_f32_16x16x32_bf16(aF[k0], bF[cur][t], acc[t], 0, 0, 0);
    }

    int rg = kq * 4;
    #pragma unroll
    for (int t = 0; t < NT; ++t) {
        int c = t * 16 + cl;
        if (c >= COLS) continue;
        float bv = bias[c];
        #pragma unroll
        for (int r = 0; r < 4; ++r) {
            int m = m0 + rg + r;
            if (m < n) out[(size_t)m * COLS + c] = fmaxf(acc[t][r] + bv, 0.f);
        }
    }
}

extern "C" void kernel_launch(void* const* d_in, const int* in_sizes, int n_in,
                              void* d_out, int out_size, void* d_ws, size_t ws_size,
                              hipStream_t stream) {
    const float* x     = (const float*)d_in[0];
    const float* hbar0 = (const float*)d_in[1];
    const float* hbar1 = (const float*)d_in[2];
    const float* W0    = (const float*)d_in[3];
    const float* b0    = (const float*)d_in[4];
    const float* W1    = (const float*)d_in[5];
    const float* b1    = (const float*)d_in[6];
    const int* hs0 = (const int*)d_in[7];
    const int* hd0 = (const int*)d_in[8];
    const int* ss0 = (const int*)d_in[9];
    const int* sd0 = (const int*)d_in[10];
    const int* hs1 = (const int*)d_in[11];
    const int* hd1 = (const int*)d_in[12];
    const int* ss1 = (const int*)d_in[13];
    const int* sd1 = (const int*)d_in[14];

    const int n   = in_sizes[0] / D_FEAT;   // 50000
    const int EH  = in_sizes[7];            // 500000
    const int ES  = in_sizes[9];            // 250000
    const int nb2 = (n + 255) / 256;        // 196 dst buckets per etype

    // ---- workspace layout ----
    int* bucketCnt = (int*)d_ws;                       // 4*nb2
    int* rpBucket  = bucketCnt + 4 * nb2;              // 4*(nb2+1)
    int* bcur      = rpBucket + 4 * (nb2 + 1);         // 4*nb2
    int* rpAll     = bcur + 4 * nb2;                   // 4*(n+1)
    int* srcAll    = rpAll + 4 * (size_t)(n + 1);      // 2EH+2ES
    unsigned* recs = (unsigned*)(srcAll + 2 * (size_t)EH + 2 * (size_t)ES); // 2EH+2ES
    size_t int_words = (size_t)12 * nb2 + 4 + 4 * (size_t)(n + 1)
                     + 4 * (size_t)EH + 4 * (size_t)ES;
    int_words = (int_words + 3) & ~(size_t)3;                          // 16 B align
    unsigned short* hb0 = (unsigned short*)((int*)d_ws + int_words);   // n*128 bf16
    unsigned short* db0 = hb0 + (size_t)n * D_FEAT;                    // n*128 bf16
    unsigned short* hb1 = db0 + (size_t)n * D_FEAT;                    // n*128 bf16
    unsigned short* db1 = hb1 + (size_t)n * D_FEAT;                    // n*128 bf16
    unsigned short* z   = db1 + (size_t)n * D_FEAT;                    // n*256 bf16 (+1 pad group)
    unsigned short* Wb0 = z + (size_t)n * K_DIM + 4096;                // 128*256 (pad: tail group reads)
    unsigned short* Wb1 = Wb0 + 128 * 256;                             // 64*256

    const int* rpH0 = rpAll;
    const int* rpS0 = rpAll + (size_t)(n + 1);
    const int* rpH1 = rpAll + 2 * (size_t)(n + 1);
    const int* rpS1 = rpAll + 3 * (size_t)(n + 1);
    int* srcH0 = srcAll;
    int* srcS0 = srcAll + (size_t)EH;
    int* srcH1 = srcAll + (size_t)EH + ES;
    int* srcS1 = srcAll + 2 * (size_t)EH + ES;

    dim3 blk(256);
    int binb  = (EH + EPB - 1) / EPB;       // 123 blocks/etype
    int prepb = ((n * 16) + 255) / 256;     // 3125
    int aggb  = (n + 3) / 4;
    int gemmb0 = (n + 31) / 32;   // 32 rows per block (layer-0 GEMM)
    int gemmb1 = (n + 31) / 32;   // 32 rows per block (layer-1 GEMM, 128 thr)

    // ---- CSR build + static prep (binA/prep/conv fused) ----
    hipMemsetAsync(bucketCnt, 0, 4 * (size_t)nb2 * sizeof(int), stream);
    histB<<<dim3(binb, 4), blk, 0, stream>>>(hd0, sd0, hd1, sd1, EH, ES, bucketCnt, nb2);
    scanBuckets<<<4, blk, 0, stream>>>(bucketCnt, rpBucket, bcur, nb2);
    binPrep<<<4 * binb + prepb + 16, blk, 0, stream>>>(
        hs0, hd0, ss0, sd0, hs1, hd1, ss1, sd1, EH, ES, bcur, recs, nb2, binb,
        (const float4*)x, (const float4*)hbar0, (const float4*)hbar1,
        (uint4*)hb0, (uint4*)db0, (uint4*)hb1, (uint4*)z, n * 16, prepb,
        W0, Wb0, W1, Wb1);
    placeB<<<dim3(nb2, 4), blk, 0, stream>>>(recs, rpBucket, rpAll, srcAll, EH, ES, n, nb2);

    // ---------------- Layer 0 ----------------
    aggregate_z<<<aggb, blk, 0, stream>>>((const uint4*)hb0, (const uint4*)db0,
                                          rpH0, srcH0, rpS0, srcS0, (uint4*)z, n);
    gemm_mfma_l0<<<gemmb0, blk, 0, stream>>>(z, Wb0, b0, hbar1, db1, z, n);

    // ---------------- Layer 1 ----------------
    aggregate_z<<<aggb, blk, 0, stream>>>((const uint4*)hb1, (const uint4*)db1,
                                          rpH1, srcH1, rpS1, srcS1, (uint4*)z, n);
    gemm_mfma<3><<<gemmb1, dim3(128), 0, stream>>>(z, Wb1, b1, (float*)d_out, n, 47);
}

// Round 9
// 286.176 us; speedup vs baseline: 1.3810x; 1.0202x over previous
//
#include <hip/hip_runtime.h>

// N=50000, D=128 (both layers), K=256, EH=500000, ES=250000.
#define D_FEAT 128
#define K_DIM  256
#define EPB 4096    // edges per binA block (r6: smaller is WORSE)
#define PADL 136    // LDS leading dim (ushorts) for the 32x128 epilogue tile
#define BCAP 4096   // arena slots per bucket (mean 2560, >25 sigma headroom)

// ---- fragment-major layouts (eliminates 64-line address divergence in GEMMs) ----
// Wb (layer L, NT tiles): slot ((k0*NT + T)*64 + lane) * 8 shorts
// z  (A operand):        slot ((G*8 + k0)*64 + lane) * 8 shorts,  G = row group of 16

typedef __attribute__((ext_vector_type(8))) short bf16x8;
typedef __attribute__((ext_vector_type(4))) float f32x4;
typedef __attribute__((ext_vector_type(2))) float f32x2;

__device__ __forceinline__ unsigned short f2b(float f) {
    union { float f; unsigned u; } cv; cv.f = f;
    return (unsigned short)((cv.u + 0x7fffu + ((cv.u >> 16) & 1u)) >> 16);
}

__device__ __forceinline__ unsigned pack2(float lo, float hi) {
    return (unsigned)f2b(lo) | ((unsigned)f2b(hi) << 16);
}

__device__ __forceinline__ uint4 pack8(float4 a, float4 b) {
    return make_uint4(pack2(a.x, a.y), pack2(a.z, a.w), pack2(b.x, b.y), pack2(b.z, b.w));
}

__device__ __forceinline__ f32x2 up2(unsigned u) {
    union { unsigned u; float f; } lo, hi;
    lo.u = u << 16; hi.u = u & 0xffff0000u;
    f32x2 r; r.x = lo.f; r.y = hi.f; return r;
}

__device__ __forceinline__ void addu4p(f32x2* a, uint4 v) {
    a[0] += up2(v.x); a[1] += up2(v.y); a[2] += up2(v.z); a[3] += up2(v.w);
}

__device__ __forceinline__ float blo(unsigned u) { union { unsigned u; float f; } c; c.u = u << 16; return c.f; }
__device__ __forceinline__ float bhi(unsigned u) { union { unsigned u; float f; } c; c.u = u & 0xffff0000u; return c.f; }

// edge-array offset within the concatenated [H0|S0|H1|S1] space
__device__ __forceinline__ long yoff(int y, int EH, int ES) {
    return (long)((y + 1) >> 1) * EH + (long)(y >> 1) * ES;
}

// ---------------- arena cursor init (replaces memset + histB + pre-scan) ----------------
__global__ __launch_bounds__(256)
void initCur(int* __restrict__ bcur, int total) {
    int i = blockIdx.x * 256 + threadIdx.x;
    if (i < total) bcur[i] = i * BCAP;
}

// ---------------- fused binA(arena) + prep_static + conv_weights ----------------
// Blocks [0, 4*binb): record scatter into per-bucket arena regions (latency/atomic bound).
// Blocks [4*binb, +prepb): bf16 prep (streaming, BW-bound).  Blocks [.., +16): weights.
// Complementary bottlenecks overlap (r7: binPrep 49us vs ~63 serial).
// dst values register-staged across the two passes (no re-read).
__global__ __launch_bounds__(256)
void binPrep(const int* __restrict__ hs0, const int* __restrict__ hd0,
             const int* __restrict__ ss0, const int* __restrict__ sd0,
             const int* __restrict__ hs1, const int* __restrict__ hd1,
             const int* __restrict__ ss1, const int* __restrict__ sd1,
             int EH, int ES, int* __restrict__ bcur, unsigned* __restrict__ arena,
             int nb2, int binb,
             const float4* __restrict__ x, const float4* __restrict__ hbar0,
             const float4* __restrict__ hbar1,
             uint4* __restrict__ hb0, uint4* __restrict__ db0,
             uint4* __restrict__ hb1, uint4* __restrict__ z, int n16, int prepb,
             const float* __restrict__ W0, unsigned short* __restrict__ WbF0,
             const float* __restrict__ W1, unsigned short* __restrict__ WbF1) {
    __shared__ int cnt[256];
    int bid = blockIdx.x;
    int t = threadIdx.x;

    if (bid < 4 * binb) {
        int y = bid / binb, c = bid % binb;
        const int* src = (y == 0) ? hs0 : (y == 1) ? ss0 : (y == 2) ? hs1 : ss1;
        const int* dst = (y == 0) ? hd0 : (y == 1) ? sd0 : (y == 2) ? hd1 : sd1;
        int E = (y & 1) ? ES : EH;

        cnt[t] = 0;
        __syncthreads();
        int i0 = c * EPB;
        int dv[16];
        #pragma unroll
        for (int j = 0; j < 16; ++j) {
            int i = i0 + j * 256 + t;
            dv[j] = (i < E) ? dst[i] : -1;
            if (dv[j] >= 0) atomicAdd(&cnt[dv[j] >> 8], 1);
        }
        __syncthreads();
        int cc = cnt[t];
        __syncthreads();
        // reserve contiguous chunk in bucket t's arena region (absolute slot index)
        if (t < nb2 && cc > 0) cnt[t] = atomicAdd(&bcur[y * nb2 + t], cc);
        __syncthreads();
        #pragma unroll
        for (int j = 0; j < 16; ++j) {
            if (dv[j] >= 0) {
                int i = i0 + j * 256 + t;
                int slot = atomicAdd(&cnt[dv[j] >> 8], 1);
                arena[slot] = (unsigned)src[i] | ((unsigned)(dv[j] & 255) << 24);
            }
        }
    } else if (bid < 4 * binb + prepb) {
        int i = (bid - 4 * binb) * 256 + t;
        if (i >= n16) return;
        float4 xa = x[i * 2],     xb = x[i * 2 + 1];
        float4 ba = hbar0[i * 2], bb = hbar0[i * 2 + 1];
        float4 ca = hbar1[i * 2], cb = hbar1[i * 2 + 1];
        hb0[i] = pack8(ba, bb);
        db0[i] = pack8(make_float4(xa.x - ba.x, xa.y - ba.y, xa.z - ba.z, xa.w - ba.w),
                       make_float4(xb.x - bb.x, xb.y - bb.y, xb.z - bb.z, xb.w - bb.w));
        hb1[i] = pack8(ca, cb);
        int g = i >> 4, seg = i & 15;
        int G = g >> 4, r = g & 15, k0 = seg >> 2, kq = seg & 3;
        z[((size_t)G * 8 + k0) * 64 + kq * 16 + r] = pack8(xa, xb);   // fragment-major
    } else {
        int i = (bid - 4 * binb - prepb) * 256 + t;
        if (i < 4096) {
            int k0 = i >> 9, T = (i >> 6) & 7, lane = i & 63;
            int col = T * 16 + (lane & 15);
            int kb = k0 * 32 + (lane >> 4) * 8;
            const float* src = W0 + (size_t)col * 256 + kb;
            unsigned short* dst = WbF0 + (size_t)i * 8;
            #pragma unroll
            for (int e = 0; e < 8; ++e) dst[e] = f2b(src[e]);
        }
        if (i < 1536) {
            int k0 = i / 192, rem = i % 192;
            int T = rem >> 6, lane = rem & 63;
            int col = T * 16 + (lane & 15);
            int kb = k0 * 32 + (lane >> 4) * 8;
            unsigned short* dst = WbF1 + (size_t)i * 8;
            #pragma unroll
            for (int e = 0; e < 8; ++e)
                dst[e] = (col < 47) ? f2b(W1[(size_t)col * 256 + kb + e]) : (unsigned short)0;
        }
    }
}

// ---------------- bucket-count scan AFTER binA (counts from final cursors) ----------------
__global__ __launch_bounds__(256)
void scanB2(const int* __restrict__ bcur, int* __restrict__ rpBucket,
            int nb2, int EH, int ES) {
    int y = blockIdx.x, t = threadIdx.x;
    __shared__ int sh[256];
    int c = (t < nb2) ? (bcur[y * nb2 + t] - (y * nb2 + t) * BCAP) : 0;
    sh[t] = c;
    __syncthreads();
    for (int o = 1; o < 256; o <<= 1) {
        int v = (t >= o) ? sh[t - o] : 0;
        __syncthreads();
        sh[t] += v;
        __syncthreads();
    }
    if (t < nb2) rpBucket[y * (nb2 + 1) + t] = sh[t] - c;
    if (t == 0) rpBucket[y * (nb2 + 1) + nb2] = (y & 1) ? ES : EH;
}

// ---------------- placeB: arena -> compact srcAll (single pass, LDS-cached) ----------------
__global__ __launch_bounds__(256)
void placeB(const unsigned* __restrict__ arena, const int* __restrict__ bcur,
            const int* __restrict__ rpBucket,
            int* __restrict__ rpAll, int* __restrict__ srcAll,
            int EH, int ES, int n, int nb2) {
    int y = blockIdx.y;
    int b = blockIdx.x;
    int E = (y & 1) ? ES : EH;
    int ybb = y * nb2 + b;
    int* rp = rpAll + (size_t)y * (n + 1);
    const unsigned* rb = arena + (size_t)ybb * BCAP;
    int* sb = srcAll + yoff(y, EH, ES);
    int ne = bcur[ybb] - ybb * BCAP;
    int e0 = rpBucket[y * (nb2 + 1) + b];
    int nodeBase = b << 8;

    __shared__ unsigned eb[BCAP];
    __shared__ int cnt[256];
    __shared__ int sh[256];
    int t = threadIdx.x;
    cnt[t] = 0;
    __syncthreads();
    for (int e = t; e < ne; e += 256) {
        unsigned r = rb[e];
        if (e < BCAP) eb[e] = r;
        atomicAdd(&cnt[r >> 24], 1);
    }
    __syncthreads();
    sh[t] = cnt[t];
    __syncthreads();
    for (int o = 1; o < 256; o <<= 1) {
        int v = (t >= o) ? sh[t - o] : 0;
        __syncthreads();
        sh[t] += v;
        __syncthreads();
    }
    int base = e0 + (t ? sh[t - 1] : 0);
    if (nodeBase + t < n) rp[nodeBase + t] = base;
    if (b == 0 && t == 0) rp[n] = E;
    cnt[t] = base;
    __syncthreads();
    for (int e = t; e < ne; e += 256) {
        unsigned r = (e < BCAP) ? eb[e] : rb[e];
        int p = atomicAdd(&cnt[r >> 24], 1);
        sb[p] = (int)(r & 0x00FFFFFFu);
    }
}

// ---------------- aggregation: one full wave per node (proven 43.2us floor) ----------------
__global__ __launch_bounds__(256)
void aggregate_z(const uint4* __restrict__ HB, const uint4* __restrict__ DB,
                 const int* __restrict__ rpH, const int* __restrict__ srcH,
                 const int* __restrict__ rpS, const int* __restrict__ srcS,
                 uint4* __restrict__ z, int n) {
    int g = blockIdx.x * 4 + (threadIdx.x >> 6);
    if (g >= n) return;
    int lane = threadIdx.x & 63;
    int j = lane >> 4, l = lane & 15;

    int hb_ = rpH[g], he = rpH[g + 1];
    int sb  = rpS[g], se = rpS[g + 1];
    int dH = he - hb_, dS = se - sb;
    int nIt = max((dH + 7) >> 3, (dS + 7) >> 3);

    f32x2 a[4] = {};
    f32x2 d[4] = {};

    int iH1 = hb_ + j, iH2 = hb_ + 4 + j;
    int iS1 = sb + j,  iS2 = sb + 4 + j;
    int sH1 = 0, sH2 = 0, sS1 = 0, sS2 = 0;
    if (iH1 < he) sH1 = srcH[iH1];
    if (iH2 < he) sH2 = srcH[iH2];
    if (iS1 < se) sS1 = srcS[iS1];
    if (iS2 < se) sS2 = srcS[iS2];

    for (int it = 0; it < nIt; ++it) {
        uint4 h1 = make_uint4(0, 0, 0, 0), h2 = make_uint4(0, 0, 0, 0);
        uint4 s1 = make_uint4(0, 0, 0, 0), s2 = make_uint4(0, 0, 0, 0);
        if (iH1 < he) h1 = HB[(size_t)sH1 * 16 + l];
        if (iH2 < he) h2 = HB[(size_t)sH2 * 16 + l];
        if (iS1 < se) s1 = DB[(size_t)sS1 * 16 + l];
        if (iS2 < se) s2 = DB[(size_t)sS2 * 16 + l];
        iH1 += 8; iH2 += 8; iS1 += 8; iS2 += 8;
        if (iH1 < he) sH1 = srcH[iH1];
        if (iH2 < he) sH2 = srcH[iH2];
        if (iS1 < se) sS1 = srcS[iS1];
        if (iS2 < se) sS2 = srcS[iS2];
        addu4p(a, h1); addu4p(a, h2);
        addu4p(d, s1); addu4p(d, s2);
    }

    float rH = 1.0f / fmaxf((float)dH, 1.0f);
    float rS = 1.0f / fmaxf((float)dS, 1.0f);
    float s[8];
    #pragma unroll
    for (int i = 0; i < 4; ++i) {
        float v0 = a[i].x * rH + d[i].x * rS;
        float v1 = a[i].y * rH + d[i].y * rS;
        v0 += __shfl_xor(v0, 16);
        v0 += __shfl_xor(v0, 32);
        v1 += __shfl_xor(v1, 16);
        v1 += __shfl_xor(v1, 32);
        s[2 * i] = v0;
        s[2 * i + 1] = v1;
    }
    if (j == 0) {
        uint4 rv = make_uint4(pack2(s[0], s[1]), pack2(s[2], s[3]),
                              pack2(s[4], s[5]), pack2(s[6], s[7]));
        size_t slot = ((size_t)(g >> 4) * 8 + 4 + (l >> 2)) * 64 + (l & 3) * 16 + (g & 15);
        z[slot] = rv;
    }
}

// ---------------- fused: gemm_l0 (streaming/MFMA) || layer-1 H-mean (gather) ----------------
// Blocks [0, gemmb): gemm layer 0 with fused relu/db1/zl epilogue.
// Blocks [gemmb, +aggb): layer-1 HISTORY mean (hb1 gather, independent of layer 0) -> hm1.
// Complementary pairing (gemm streams, agg gathers) per the r7 binPrep result.
__global__ __launch_bounds__(256, 2)
void gemmAgg(const unsigned short* __restrict__ Z, const unsigned short* __restrict__ Wb,
             const float* __restrict__ bias, const float* __restrict__ hbar1,
             unsigned short* __restrict__ db1, unsigned short* __restrict__ zl, int n,
             int gemmb,
             const uint4* __restrict__ HB1, const int* __restrict__ rpH1,
             const int* __restrict__ srcH1, uint4* __restrict__ hm1) {
    __shared__ unsigned short hl[32 * PADL];
    int bid = blockIdx.x;
    int tid = threadIdx.x;
    int lane = tid & 63;

    if (bid < gemmb) {
        int wave = tid >> 6;
        int rt = wave >> 1;
        int ch = wave & 1;
        int m0 = bid * 32;
        int cl = lane & 15;
        int kq = lane >> 4;

        const short* Af = (const short*)Z;
        const short* Bf = (const short*)Wb;
        size_t G = (size_t)(m0 >> 4) + rt;

        bf16x8 aF[8];
        #pragma unroll
        for (int k0 = 0; k0 < 8; ++k0)
            aF[k0] = *(const bf16x8*)(Af + ((G * 8 + k0) * 64 + lane) * 8);

        f32x4 acc[4] = {};
        bf16x8 bF[2][4];
        #pragma unroll
        for (int t = 0; t < 4; ++t)
            bF[0][t] = *(const bf16x8*)(Bf + ((size_t)((ch * 4 + t)) * 64 + lane) * 8);

        #pragma unroll
        for (int k0 = 0; k0 < 8; ++k0) {
            int cur = k0 & 1, nxt = cur ^ 1;
            if (k0 < 7) {
                #pragma unroll
                for (int t = 0; t < 4; ++t)
                    bF[nxt][t] = *(const bf16x8*)(Bf + ((size_t)(((k0 + 1) * 8 + ch * 4 + t)) * 64 + lane) * 8);
            }
            #pragma unroll
            for (int t = 0; t < 4; ++t)
                acc[t] = __builtin_amdgcn_mfma_f32_16x16x32_bf16(aF[k0], bF[cur][t], acc[t], 0, 0, 0);
        }

        #pragma unroll
        for (int t = 0; t < 4; ++t) {
            int c = ch * 64 + t * 16 + cl;
            float bv = bias[c];
            #pragma unroll
            for (int r = 0; r < 4; ++r) {
                int row = rt * 16 + kq * 4 + r;
                hl[row * PADL + c] = f2b(fmaxf(acc[t][r] + bv, 0.0f));
            }
        }
        __syncthreads();

        // zl (layer-1 A operand) written FRAGMENT-MAJOR: 512 slots of 16B, coalesced.
        #pragma unroll
        for (int s = 0; s < 2; ++s) {
            int ls = tid + s * 256;
            int gi = ls >> 8, k0 = (ls >> 6) & 3, ln = ls & 63;
            int rl = gi * 16 + (ln & 15);
            int col = k0 * 32 + (ln >> 4) * 8;
            int m = m0 + rl;
            if (m < n) {
                uint4 v = *(const uint4*)(hl + rl * PADL + col);
                ((uint4*)zl)[((size_t)(m0 >> 4) + gi) * 8 * 64 + (size_t)k0 * 64 + ln] = v;
            }
        }

        // db1 = bf16(h - hbar1), row-major (gather target), coalesced
        int row  = tid >> 3;
        int col  = (tid & 7) * 16;
        int m    = m0 + row;
        if (m < n) {
            const uint4* hr = (const uint4*)(hl + row * PADL + col);
            uint4 v0 = hr[0];
            uint4 v1 = hr[1];
            const float4* hb = (const float4*)(hbar1 + (size_t)m * 128 + col);
            float4 h0 = hb[0], h1 = hb[1], h2 = hb[2], h3 = hb[3];
            uint4 d0, d1;
            d0.x = pack2(blo(v0.x) - h0.x, bhi(v0.x) - h0.y);
            d0.y = pack2(blo(v0.y) - h0.z, bhi(v0.y) - h0.w);
            d0.z = pack2(blo(v0.z) - h1.x, bhi(v0.z) - h1.y);
            d0.w = pack2(blo(v0.w) - h1.z, bhi(v0.w) - h1.w);
            d1.x = pack2(blo(v1.x) - h2.x, bhi(v1.x) - h2.y);
            d1.y = pack2(blo(v1.y) - h2.z, bhi(v1.y) - h2.w);
            d1.z = pack2(blo(v1.z) - h3.x, bhi(v1.z) - h3.y);
            d1.w = pack2(blo(v1.w) - h3.z, bhi(v1.w) - h3.w);
            uint4* dp = (uint4*)(db1 + (size_t)m * 128 + col);
            dp[0] = d0;
            dp[1] = d1;
        }
    } else {
        // ---- layer-1: history mean only -> hm1 (row-major bf16). 4 H-slots/lane. ----
        int g = (bid - gemmb) * 4 + (tid >> 6);
        if (g >= n) return;
        int j = lane >> 4, l = lane & 15;
        int hb_ = rpH1[g], he = rpH1[g + 1];
        int dH = he - hb_;
        int nIt = (dH + 15) >> 4;

        f32x2 a[4] = {};
        int iH1 = hb_ + j, iH2 = hb_ + 4 + j, iH3 = hb_ + 8 + j, iH4 = hb_ + 12 + j;
        int sH1 = 0, sH2 = 0, sH3 = 0, sH4 = 0;
        if (iH1 < he) sH1 = srcH1[iH1];
        if (iH2 < he) sH2 = srcH1[iH2];
        if (iH3 < he) sH3 = srcH1[iH3];
        if (iH4 < he) sH4 = srcH1[iH4];

        for (int it = 0; it < nIt; ++it) {
            uint4 h1 = make_uint4(0,0,0,0), h2 = make_uint4(0,0,0,0);
            uint4 h3 = make_uint4(0,0,0,0), h4 = make_uint4(0,0,0,0);
            if (iH1 < he) h1 = HB1[(size_t)sH1 * 16 + l];
            if (iH2 < he) h2 = HB1[(size_t)sH2 * 16 + l];
            if (iH3 < he) h3 = HB1[(size_t)sH3 * 16 + l];
            if (iH4 < he) h4 = HB1[(size_t)sH4 * 16 + l];
            iH1 += 16; iH2 += 16; iH3 += 16; iH4 += 16;
            if (iH1 < he) sH1 = srcH1[iH1];
            if (iH2 < he) sH2 = srcH1[iH2];
            if (iH3 < he) sH3 = srcH1[iH3];
            if (iH4 < he) sH4 = srcH1[iH4];
            addu4p(a, h1); addu4p(a, h2); addu4p(a, h3); addu4p(a, h4);
        }

        float rH = 1.0f / fmaxf((float)dH, 1.0f);
        float s[8];
        #pragma unroll
        for (int i = 0; i < 4; ++i) {
            float v0 = a[i].x * rH;
            float v1 = a[i].y * rH;
            v0 += __shfl_xor(v0, 16);
            v0 += __shfl_xor(v0, 32);
            v1 += __shfl_xor(v1, 16);
            v1 += __shfl_xor(v1, 32);
            s[2 * i] = v0;
            s[2 * i + 1] = v1;
        }
        if (j == 0) {
            uint4 rv = make_uint4(pack2(s[0], s[1]), pack2(s[2], s[3]),
                                  pack2(s[4], s[5]), pack2(s[6], s[7]));
            hm1[(size_t)g * 16 + l] = rv;
        }
    }
}

// ---------------- layer-1 sampled aggregation (post-gemmAgg; proven r4) ----------------
__global__ __launch_bounds__(256)
void agg_s1(const uint4* __restrict__ DB1, const int* __restrict__ rpS,
            const int* __restrict__ srcS, const uint4* __restrict__ hm1,
            uint4* __restrict__ z, int n) {
    int g = blockIdx.x * 4 + (threadIdx.x >> 6);
    if (g >= n) return;
    int lane = threadIdx.x & 63;
    int j = lane >> 4, l = lane & 15;

    int sb = rpS[g], se = rpS[g + 1];
    int dS = se - sb;
    int nIt = (dS + 7) >> 3;

    f32x2 d[4] = {};
    int iS1 = sb + j, iS2 = sb + 4 + j;
    int sS1 = 0, sS2 = 0;
    if (iS1 < se) sS1 = srcS[iS1];
    if (iS2 < se) sS2 = srcS[iS2];

    for (int it = 0; it < nIt; ++it) {
        uint4 s1 = make_uint4(0,0,0,0), s2 = make_uint4(0,0,0,0);
        if (iS1 < se) s1 = DB1[(size_t)sS1 * 16 + l];
        if (iS2 < se) s2 = DB1[(size_t)sS2 * 16 + l];
        iS1 += 8; iS2 += 8;
        if (iS1 < se) sS1 = srcS[iS1];
        if (iS2 < se) sS2 = srcS[iS2];
        addu4p(d, s1); addu4p(d, s2);
    }

    float rS = 1.0f / fmaxf((float)dS, 1.0f);
    float s[8];
    #pragma unroll
    for (int i = 0; i < 4; ++i) {
        float v0 = d[i].x * rS;
        float v1 = d[i].y * rS;
        v0 += __shfl_xor(v0, 16);
        v0 += __shfl_xor(v0, 32);
        v1 += __shfl_xor(v1, 16);
        v1 += __shfl_xor(v1, 32);
        s[2 * i] = v0;
        s[2 * i + 1] = v1;
    }
    if (j == 0) {
        uint4 hm = hm1[(size_t)g * 16 + l];
        s[0] += blo(hm.x); s[1] += bhi(hm.x);
        s[2] += blo(hm.y); s[3] += bhi(hm.y);
        s[4] += blo(hm.z); s[5] += bhi(hm.z);
        s[6] += blo(hm.w); s[7] += bhi(hm.w);
        uint4 rv = make_uint4(pack2(s[0], s[1]), pack2(s[2], s[3]),
                              pack2(s[4], s[5]), pack2(s[6], s[7]));
        size_t slot = ((size_t)(g >> 4) * 8 + 4 + (l >> 2)) * 64 + (l & 3) * 16 + (g & 15);
        z[slot] = rv;
    }
}

// ---------------- MFMA GEMM layer 1 -> f32 out ----------------
template<int NT>
__global__ __launch_bounds__(128, 2)
void gemm_mfma(const unsigned short* __restrict__ Z, const unsigned short* __restrict__ Wb,
               const float* __restrict__ bias, float* __restrict__ out, int n, int COLS) {
    int wave = threadIdx.x >> 6;
    int lane = threadIdx.x & 63;
    int m0 = blockIdx.x * 32 + wave * 16;
    int cl = lane & 15;
    int kq = lane >> 4;

    const short* Af = (const short*)Z;
    const short* Bf = (const short*)Wb;
    size_t G = (size_t)(m0 >> 4);

    bf16x8 aF[8];
    #pragma unroll
    for (int k0 = 0; k0 < 8; ++k0)
        aF[k0] = *(const bf16x8*)(Af + ((G * 8 + k0) * 64 + lane) * 8);

    f32x4 acc[NT] = {};
    bf16x8 bF[2][NT];
    #pragma unroll
    for (int t = 0; t < NT; ++t)
        bF[0][t] = *(const bf16x8*)(Bf + ((size_t)(0 * NT + t) * 64 + lane) * 8);

    #pragma unroll
    for (int k0 = 0; k0 < 8; ++k0) {
        int cur = k0 & 1, nxt = cur ^ 1;
        if (k0 < 7) {
            #pragma unroll
            for (int t = 0; t < NT; ++t)
                bF[nxt][t] = *(const bf16x8*)(Bf + ((size_t)((k0 + 1) * NT + t) * 64 + lane) * 8);
        }
        #pragma unroll
        for (int t = 0; t < NT; ++t)
            acc[t] = __builtin_amdgcn_mfma_f32_16x16x32_bf16(aF[k0], bF[cur][t], acc[t], 0, 0, 0);
    }

    int rg = kq * 4;
    #pragma unroll
    for (int t = 0; t < NT; ++t) {
        int c = t * 16 + cl;
        if (c >= COLS) continue;
        float bv = bias[c];
        #pragma unroll
        for (int r = 0; r < 4; ++r) {
            int m = m0 + rg + r;
            if (m < n) out[(size_t)m * COLS + c] = fmaxf(acc[t][r] + bv, 0.f);
        }
    }
}

extern "C" void kernel_launch(void* const* d_in, const int* in_sizes, int n_in,
                              void* d_out, int out_size, void* d_ws, size_t ws_size,
                              hipStream_t stream) {
    const float* x     = (const float*)d_in[0];
    const float* hbar0 = (const float*)d_in[1];
    const float* hbar1 = (const float*)d_in[2];
    const float* W0    = (const float*)d_in[3];
    const float* b0    = (const float*)d_in[4];
    const float* W1    = (const float*)d_in[5];
    const float* b1    = (const float*)d_in[6];
    const int* hs0 = (const int*)d_in[7];
    const int* hd0 = (const int*)d_in[8];
    const int* ss0 = (const int*)d_in[9];
    const int* sd0 = (const int*)d_in[10];
    const int* hs1 = (const int*)d_in[11];
    const int* hd1 = (const int*)d_in[12];
    const int* ss1 = (const int*)d_in[13];
    const int* sd1 = (const int*)d_in[14];

    const int n   = in_sizes[0] / D_FEAT;   // 50000
    const int EH  = in_sizes[7];            // 500000
    const int ES  = in_sizes[9];            // 250000
    const int nb2 = (n + 255) / 256;        // 196 dst buckets per etype

    // ---- workspace layout ----
    int* bcur      = (int*)d_ws;                        // 4*nb2 arena cursors
    int* rpBucket  = bcur + 4 * nb2;                    // 4*(nb2+1)
    int* rpAll     = rpBucket + 4 * (nb2 + 1);          // 4*(n+1)
    int* srcAll    = rpAll + 4 * (size_t)(n + 1);       // 2EH+2ES
    unsigned* arena = (unsigned*)(srcAll + 2 * (size_t)EH + 2 * (size_t)ES); // 4*nb2*BCAP
    size_t int_words = (size_t)4 * nb2 + 4 * (nb2 + 1) + 4 * (size_t)(n + 1)
                     + 2 * (size_t)EH + 2 * (size_t)ES + (size_t)4 * nb2 * BCAP;
    int_words = (int_words + 3) & ~(size_t)3;                          // 16 B align
    unsigned short* hb0 = (unsigned short*)((int*)d_ws + int_words);   // n*128 bf16
    unsigned short* db0 = hb0 + (size_t)n * D_FEAT;                    // n*128 bf16
    unsigned short* hb1 = db0 + (size_t)n * D_FEAT;                    // n*128 bf16
    unsigned short* db1 = hb1 + (size_t)n * D_FEAT;                    // n*128 bf16
    unsigned short* z   = db1 + (size_t)n * D_FEAT;                    // n*256 bf16 (+1 pad group)
    unsigned short* Wb0 = z + (size_t)n * K_DIM + 4096;                // 128*256 (pad: tail group reads)
    unsigned short* Wb1 = Wb0 + 128 * 256;                             // 64*256
    unsigned short* hm1 = Wb1 + 64 * 256;                              // n*128 bf16 (layer-1 hist mean)

    const int* rpH0 = rpAll;
    const int* rpS0 = rpAll + (size_t)(n + 1);
    const int* rpH1 = rpAll + 2 * (size_t)(n + 1);
    const int* rpS1 = rpAll + 3 * (size_t)(n + 1);
    int* srcH0 = srcAll;
    int* srcS0 = srcAll + (size_t)EH;
    int* srcH1 = srcAll + (size_t)EH + ES;
    int* srcS1 = srcAll + 2 * (size_t)EH + ES;

    dim3 blk(256);
    int binb  = (EH + EPB - 1) / EPB;       // 123 blocks/etype
    int prepb = ((n * 16) + 255) / 256;     // 3125
    int aggb  = (n + 3) / 4;                // 12500
    int gemmb0 = (n + 31) / 32;             // 1563
    int gemmb1 = (n + 31) / 32;

    // ---- CSR build (arena; no histB/memset) + static prep ----
    initCur<<<4, blk, 0, stream>>>(bcur, 4 * nb2);
    binPrep<<<4 * binb + prepb + 16, blk, 0, stream>>>(
        hs0, hd0, ss0, sd0, hs1, hd1, ss1, sd1, EH, ES, bcur, arena, nb2, binb,
        (const float4*)x, (const float4*)hbar0, (const float4*)hbar1,
        (uint4*)hb0, (uint4*)db0, (uint4*)hb1, (uint4*)z, n * 16, prepb,
        W0, Wb0, W1, Wb1);
    scanB2<<<4, blk, 0, stream>>>(bcur, rpBucket, nb2, EH, ES);
    placeB<<<dim3(nb2, 4), blk, 0, stream>>>(arena, bcur, rpBucket, rpAll, srcAll,
                                             EH, ES, n, nb2);

    // ---------------- Layer 0 aggregation ----------------
    aggregate_z<<<aggb, blk, 0, stream>>>((const uint4*)hb0, (const uint4*)db0,
                                          rpH0, srcH0, rpS0, srcS0, (uint4*)z, n);

    // ---------------- gemm layer 0 || layer-1 history mean ----------------
    gemmAgg<<<gemmb0 + aggb, blk, 0, stream>>>(z, Wb0, b0, hbar1, db1, z, n, gemmb0,
                                               (const uint4*)hb1, rpH1, srcH1, (uint4*)hm1);

    // ---------------- Layer 1: sampled aggregation + GEMM ----------------
    agg_s1<<<aggb, blk, 0, stream>>>((const uint4*)db1, rpS1, srcS1, (const uint4*)hm1,
                                     (uint4*)z, n);
    gemm_mfma<3><<<gemmb1, dim3(128), 0, stream>>>(z, Wb1, b1, (float*)d_out, n, 47);
}